// Round 14
// baseline (235.360 us; speedup 1.0000x reference)
//
#include <hip/hip_runtime.h>

#define NN 50000
#define NE 800000
#define NL 200000
#define NB_SCAN 196  // ceil(50000/256)

typedef __attribute__((ext_vector_type(8))) short bf16x8;
typedef __attribute__((ext_vector_type(4))) float f32x4;

__device__ __forceinline__ ushort bf16_rne(float f) {
    union { float f; unsigned u; } v; v.f = f;
    unsigned r = v.u + 0x7FFF + ((v.u >> 16) & 1);
    return (ushort)(r >> 16);
}
__device__ __forceinline__ float bf16_to_f(ushort h) {
    union { unsigned u; float f; } v; v.u = ((unsigned)h) << 16;
    return v.f;
}
__device__ __forceinline__ float lo_f(unsigned u) {
    union { unsigned u; float f; } v; v.u = u << 16;
    return v.f;
}
__device__ __forceinline__ float hi_f(unsigned u) {
    union { unsigned u; float f; } v; v.u = u & 0xffff0000u;
    return v.f;
}

// ---------------- CSR build ----------------

__global__ void k_count(const int* __restrict__ tgt, int* __restrict__ counts,
                        int* __restrict__ rank) {
    int e = blockIdx.x * blockDim.x + threadIdx.x;
    if (e < NE) rank[e] = atomicAdd(&counts[tgt[e]], 1);
}

__global__ void k_scan1(const int* __restrict__ counts, int* __restrict__ bsum) {
    int i = blockIdx.x * 256 + threadIdx.x;
    int v = (i < NN) ? counts[i] : 0;
    #pragma unroll
    for (int off = 32; off; off >>= 1) v += __shfl_down(v, off, 64);
    __shared__ int ws4[4];
    int wave = threadIdx.x >> 6, lane = threadIdx.x & 63;
    if (lane == 0) ws4[wave] = v;
    __syncthreads();
    if (threadIdx.x == 0) bsum[blockIdx.x] = ws4[0] + ws4[1] + ws4[2] + ws4[3];
}

__global__ void k_scan2(int* __restrict__ bsum, int nb) {
    __shared__ int s[256];
    int t = threadIdx.x;
    int v = (t < nb) ? bsum[t] : 0;
    s[t] = v;
    __syncthreads();
    for (int off = 1; off < 256; off <<= 1) {
        int a = (t >= off) ? s[t - off] : 0;
        __syncthreads();
        s[t] += a;
        __syncthreads();
    }
    if (t < nb) bsum[t] = s[t] - v;  // exclusive
}

__global__ void k_scan3(const int* __restrict__ counts, const int* __restrict__ boff,
                        int* __restrict__ rowptr) {
    __shared__ int s[256];
    int t = threadIdx.x;
    int i = blockIdx.x * 256 + t;
    int v = (i < NN) ? counts[i] : 0;
    s[t] = v;
    __syncthreads();
    for (int off = 1; off < 256; off <<= 1) {
        int a = (t >= off) ? s[t - off] : 0;
        __syncthreads();
        s[t] += a;
        __syncthreads();
    }
    int excl = s[t] - v + boff[blockIdx.x];
    if (i < NN) rowptr[i] = excl;
    if (i == NN - 1) rowptr[NN] = excl + v;  // == NE
}

__global__ void k_fill(const int* __restrict__ src, const int* __restrict__ tgt,
                       const int* __restrict__ rowptr, const int* __restrict__ rank,
                       int* __restrict__ csr) {
    int e = blockIdx.x * blockDim.x + threadIdx.x;
    if (e < NE) csr[rowptr[tgt[e]] + rank[e]] = src[e];
}

// ---------------- x -> hi/lo bf16 split ----------------

__global__ void k_xcast(const float* __restrict__ x, ushort* __restrict__ xh,
                        ushort* __restrict__ xl, int n8) {
    int i = blockIdx.x * 256 + threadIdx.x;
    if (i >= n8) return;
    float4 v0 = *(const float4*)&x[i * 8];
    float4 v1 = *(const float4*)&x[i * 8 + 4];
    float av[8] = {v0.x, v0.y, v0.z, v0.w, v1.x, v1.y, v1.z, v1.w};
    ushort h[8], l[8];
    #pragma unroll
    for (int j = 0; j < 8; j++) {
        h[j] = bf16_rne(av[j]);
        l[j] = bf16_rne(av[j] - bf16_to_f(h[j]));
    }
    *(bf16x8*)&xh[i * 8] = *(bf16x8*)h;
    *(bf16x8*)&xl[i * 8] = *(bf16x8*)l;
}

// ---------------- CSR gather-mean aggregation (bf16 gather) ----------------
// OSPLIT=1: write mean as hi/lo bf16 pair. OSPLIT=0: fp32 out (+optional addp).

template <int D, int OSPLIT>
__global__ void k_aggb(const ushort* __restrict__ in,
                       const float* __restrict__ addp, int addStride,
                       float* __restrict__ outF, ushort* __restrict__ outH,
                       ushort* __restrict__ outL,
                       const int* __restrict__ rowptr, const int* __restrict__ csr) {
    constexpr int LPR = D / 8;      // lanes per row: 8 (D=64) or 16 (D=128)
    constexpr int EPW = 64 / LPR;   // edge slots: 8 or 4
    int node = blockIdx.x * 4 + (threadIdx.x >> 6);
    int lane = threadIdx.x & 63;
    if (node >= NN) return;
    int sub = lane / LPR;
    int li  = lane % LPR;           // 8-elem group within row
    int r0 = rowptr[node], r1 = rowptr[node + 1];

    float a[8] = {0.f, 0.f, 0.f, 0.f, 0.f, 0.f, 0.f, 0.f};
    float b[8] = {0.f, 0.f, 0.f, 0.f, 0.f, 0.f, 0.f, 0.f};
    int e0 = r0 + sub;
    int e1 = e0 + EPW;
    int i0 = (e0 < r1) ? csr[e0] : 0;
    int i1 = (e1 < r1) ? csr[e1] : 0;
    while (e1 < r1) {
        int e0n = e0 + 2 * EPW, e1n = e1 + 2 * EPW;
        int i0n = (e0n < r1) ? csr[e0n] : 0;
        int i1n = (e1n < r1) ? csr[e1n] : 0;
        uint4 v0 = *(const uint4*)(in + (size_t)i0 * D + li * 8);
        uint4 v1 = *(const uint4*)(in + (size_t)i1 * D + li * 8);
        a[0] += lo_f(v0.x); a[1] += hi_f(v0.x); a[2] += lo_f(v0.y); a[3] += hi_f(v0.y);
        a[4] += lo_f(v0.z); a[5] += hi_f(v0.z); a[6] += lo_f(v0.w); a[7] += hi_f(v0.w);
        b[0] += lo_f(v1.x); b[1] += hi_f(v1.x); b[2] += lo_f(v1.y); b[3] += hi_f(v1.y);
        b[4] += lo_f(v1.z); b[5] += hi_f(v1.z); b[6] += lo_f(v1.w); b[7] += hi_f(v1.w);
        e0 = e0n; e1 = e1n; i0 = i0n; i1 = i1n;
    }
    if (e0 < r1) {
        uint4 v0 = *(const uint4*)(in + (size_t)i0 * D + li * 8);
        a[0] += lo_f(v0.x); a[1] += hi_f(v0.x); a[2] += lo_f(v0.y); a[3] += hi_f(v0.y);
        a[4] += lo_f(v0.z); a[5] += hi_f(v0.z); a[6] += lo_f(v0.w); a[7] += hi_f(v0.w);
    }
    #pragma unroll
    for (int j = 0; j < 8; j++) a[j] += b[j];
    #pragma unroll
    for (int off = LPR; off < 64; off <<= 1)
        #pragma unroll
        for (int j = 0; j < 8; j++) a[j] += __shfl_xor(a[j], off, 64);
    if (sub == 0) {
        float inv = 1.0f / fmaxf((float)(r1 - r0), 1.0f);
        #pragma unroll
        for (int j = 0; j < 8; j++) a[j] *= inv;
        if constexpr (OSPLIT) {
            ushort h[8], l[8];
            #pragma unroll
            for (int j = 0; j < 8; j++) {
                h[j] = bf16_rne(a[j]);
                l[j] = bf16_rne(a[j] - bf16_to_f(h[j]));
            }
            *(bf16x8*)&outH[(size_t)node * D + li * 8] = *(bf16x8*)h;
            *(bf16x8*)&outL[(size_t)node * D + li * 8] = *(bf16x8*)l;
        } else {
            if (addp) {
                float4 p0 = *(const float4*)&addp[(size_t)node * addStride + li * 8];
                float4 p1 = *(const float4*)&addp[(size_t)node * addStride + li * 8 + 4];
                a[0] += p0.x; a[1] += p0.y; a[2] += p0.z; a[3] += p0.w;
                a[4] += p1.x; a[5] += p1.y; a[6] += p1.z; a[7] += p1.w;
            }
            *(float4*)&outF[(size_t)node * D + li * 8]     = make_float4(a[0], a[1], a[2], a[3]);
            *(float4*)&outF[(size_t)node * D + li * 8 + 4] = make_float4(a[4], a[5], a[6], a[7]);
        }
    }
}

// ---------------- weight pre-split: per-lane MFMA fragment layout ----------------
// frag[chunk][ct][lane][j] -> W[chunk*32 + (lane>>4)*8 + j][ct*16 + (lane&15)].

template <int K, int KA, int NCAT>
__global__ void k_wsplit(const float* __restrict__ W1, const float* __restrict__ W2,
                         ushort* __restrict__ hi, ushort* __restrict__ lo) {
    int id = blockIdx.x * 256 + threadIdx.x;
    if (id >= 128 * K) return;
    int col = id / K, k = id - col * K;
    float v;
    if constexpr (NCAT) {
        v = (col < 64) ? W1[(size_t)k * 64 + col] : W2[(size_t)k * 64 + (col - 64)];
    } else {
        v = (k < KA) ? W1[(size_t)k * 128 + col] : W2[(size_t)(k - KA) * 128 + col];
    }
    ushort h = bf16_rne(v);
    ushort l = bf16_rne(v - bf16_to_f(h));
    int chunk = k >> 5, kk = k & 31;
    int kg4 = kk >> 3, j = kk & 7;
    int ct = col >> 4, lr = col & 15;
    size_t dst = ((size_t)(chunk * 8 + ct) * 64 + kg4 * 16 + lr) * 8 + j;
    hi[dst] = h; lo[dst] = l;
}

// ---------------- MFMA GEMM (pre-split bf16x3 = fp32 accuracy) ----------------
// A comes PRE-SPLIT hi/lo from producers; zero conversion VALU in the loop.
// Block: 256 thr = 4 waves over 32 rows: wave w -> row-tile (w&1), col-group
// (w>>1)*4 col-tiles. Grid 1563 -> 24.4 waves/CU (2x round-11 TLP).
// C = Ah@Wh + Ah@Wl + Al@Wh. No LDS, no barriers; A prefetch 1 chunk ahead.
// MFMA layouts (m89): A[j]=A[lr][kg4*8+j], B[j]=B[kg4*8+j][lr], D[j]=C[kg4*4+j][lr].
// OMODE 1: out = hi/lo pair [n][128] (+bias,+relu).
// OMODE 2: cols 0..63 -> pb bf16 (no bias), cols 64..127 -> q fp32 (+bias).

template <int K, int KA, int RELU, int OMODE>
__launch_bounds__(256, 5)
__global__ void k_mgemm(const ushort* __restrict__ AhiA, const ushort* __restrict__ AloA,
                        const ushort* __restrict__ AhiB, const ushort* __restrict__ AloB,
                        const ushort* __restrict__ Whi, const ushort* __restrict__ Wlo,
                        const float* __restrict__ bias,
                        ushort* __restrict__ outH, ushort* __restrict__ outL,
                        ushort* __restrict__ pbOut, float* __restrict__ qOut) {
    constexpr int KB = K - KA;
    constexpr int NCH = K / 32;

    int tid = threadIdx.x;
    int wave = tid >> 6, lane = tid & 63;
    int lr  = lane & 15;
    int kg4 = lane >> 4;
    int ctg = wave >> 1;                       // col-group 0/1 (cols ctg*64..)
    int rbase = blockIdx.x * 32 + (wave & 1) * 16;
    int row = min(rbase + lr, NN - 1);

    f32x4 acc[4];
    #pragma unroll
    for (int ct = 0; ct < 4; ct++) acc[ct] = (f32x4){0.f, 0.f, 0.f, 0.f};

    auto loadApair = [&](int chunk, bf16x8& h, bf16x8& l) {
        int kg2 = chunk * 32 + kg4 * 8;
        if (kg2 < KA) {
            h = *(const bf16x8*)(AhiA + (size_t)row * KA + kg2);
            l = *(const bf16x8*)(AloA + (size_t)row * KA + kg2);
        } else {
            h = *(const bf16x8*)(AhiB + (size_t)row * KB + (kg2 - KA));
            l = *(const bf16x8*)(AloB + (size_t)row * KB + (kg2 - KA));
        }
    };

    bf16x8 ahC, alC, ahN, alN;
    loadApair(0, ahC, alC);
    ahN = ahC; alN = alC;

    #pragma unroll
    for (int chunk = 0; chunk < NCH; chunk++) {
        if (chunk + 1 < NCH) loadApair(chunk + 1, ahN, alN);  // prefetch next A
        const ushort* ph = Whi + ((size_t)(chunk * 8 + ctg * 4) * 64 + lane) * 8;
        const ushort* pl = Wlo + ((size_t)(chunk * 8 + ctg * 4) * 64 + lane) * 8;
        #pragma unroll
        for (int ct = 0; ct < 4; ct++) {
            bf16x8 wh = *(const bf16x8*)(ph + ct * 512);
            bf16x8 wl = *(const bf16x8*)(pl + ct * 512);
            acc[ct] = __builtin_amdgcn_mfma_f32_16x16x32_bf16(ahC, wh, acc[ct], 0, 0, 0);
            acc[ct] = __builtin_amdgcn_mfma_f32_16x16x32_bf16(ahC, wl, acc[ct], 0, 0, 0);
            acc[ct] = __builtin_amdgcn_mfma_f32_16x16x32_bf16(alC, wh, acc[ct], 0, 0, 0);
        }
        ahC = ahN; alC = alN;
    }

    #pragma unroll
    for (int j = 0; j < 4; j++) {
        int n = rbase + kg4 * 4 + j;
        if (n >= NN) continue;
        #pragma unroll
        for (int ct = 0; ct < 4; ct++) {
            if constexpr (OMODE == 1) {
                int c = ctg * 64 + ct * 16 + lr;
                float v = acc[ct][j] + bias[c];
                if (RELU) v = fmaxf(v, 0.f);
                ushort h = bf16_rne(v);
                outH[(size_t)n * 128 + c] = h;
                outL[(size_t)n * 128 + c] = bf16_rne(v - bf16_to_f(h));
            } else {
                int cc = ct * 16 + lr;
                if (ctg == 0) {
                    pbOut[(size_t)n * 64 + cc] = bf16_rne(acc[ct][j]);
                } else {
                    qOut[(size_t)n * 64 + cc] = acc[ct][j] + bias[cc];
                }
            }
        }
    }
}

// ---------------- decode ----------------

__global__ void k_decode(const int* __restrict__ eli, const float* __restrict__ z,
                         float* __restrict__ out) {
    int w = blockIdx.x * 4 + (threadIdx.x >> 6);
    int lane = threadIdx.x & 63;
    int sub = lane >> 4, li = lane & 15;
    int e0 = w * 8 + sub;
    int e1 = e0 + 4;
    float s0 = 0.f, s1 = 0.f;
    if (e0 < NL) {
        int a = eli[e0], b = eli[NL + e0];
        float4 va = *(const float4*)&z[(size_t)a * 64 + li * 4];
        float4 vb = *(const float4*)&z[(size_t)b * 64 + li * 4];
        s0 = va.x * vb.x + va.y * vb.y + va.z * vb.z + va.w * vb.w;
    }
    if (e1 < NL) {
        int a = eli[e1], b = eli[NL + e1];
        float4 va = *(const float4*)&z[(size_t)a * 64 + li * 4];
        float4 vb = *(const float4*)&z[(size_t)b * 64 + li * 4];
        s1 = va.x * vb.x + va.y * vb.y + va.z * vb.z + va.w * vb.w;
    }
    #pragma unroll
    for (int off = 1; off < 16; off <<= 1) {
        s0 += __shfl_xor(s0, off, 64);
        s1 += __shfl_xor(s1, off, 64);
    }
    if (li == 0) {
        if (e0 < NL) out[e0] = s0;
        if (e1 < NL) out[e1] = s1;
    }
}

// ---------------- launch ----------------

extern "C" void kernel_launch(void* const* d_in, const int* in_sizes, int n_in,
                              void* d_out, int out_size, void* d_ws, size_t ws_size,
                              hipStream_t stream) {
    const float* x   = (const float*)d_in[0];
    const int*   edge = (const int*)d_in[1];   // [2, NE]
    const int*   eli  = (const int*)d_in[2];   // [2, NL]
    const float* Wl1 = (const float*)d_in[3];
    const float* Wr1 = (const float*)d_in[4];
    const float* b1  = (const float*)d_in[5];
    const float* Wl2 = (const float*)d_in[6];
    const float* Wr2 = (const float*)d_in[7];
    const float* b2  = (const float*)d_in[8];
    const float* Wl3 = (const float*)d_in[9];
    const float* Wr3 = (const float*)d_in[10];
    const float* b3  = (const float*)d_in[11];
    float* out = (float*)d_out;

    char* w = (char*)d_ws;
    auto carve = [&](size_t bytes) {
        char* p = w;
        w += (bytes + 255) & ~(size_t)255;
        return p;
    };
    int*    rowptr = (int*)carve((NN + 1) * sizeof(int));
    int*    counts = (int*)carve(NN * sizeof(int));
    int*    rank   = (int*)carve(NE * sizeof(int));
    int*    csr    = (int*)carve(NE * sizeof(int));
    int*    bsum   = (int*)carve(256 * sizeof(int));
    float*  Z      = (float*)carve((size_t)NN * 64 * sizeof(float));    // z
    float*  Q      = (float*)carve((size_t)NN * 64 * sizeof(float));    // q
    ushort* xbh    = (ushort*)carve((size_t)NN * 64 * sizeof(ushort));
    ushort* xbl    = (ushort*)carve((size_t)NN * 64 * sizeof(ushort));
    ushort* mn1h   = (ushort*)carve((size_t)NN * 64 * sizeof(ushort));
    ushort* mn1l   = (ushort*)carve((size_t)NN * 64 * sizeof(ushort));
    ushort* h1h    = (ushort*)carve((size_t)NN * 128 * sizeof(ushort));
    ushort* h1l    = (ushort*)carve((size_t)NN * 128 * sizeof(ushort));
    ushort* mn2h   = (ushort*)carve((size_t)NN * 128 * sizeof(ushort));
    ushort* mn2l   = (ushort*)carve((size_t)NN * 128 * sizeof(ushort));
    ushort* h2h    = (ushort*)carve((size_t)NN * 128 * sizeof(ushort));
    ushort* h2l    = (ushort*)carve((size_t)NN * 128 * sizeof(ushort));
    ushort* pb     = (ushort*)carve((size_t)NN * 64 * sizeof(ushort));
    ushort* W1h    = (ushort*)carve(128 * 128 * sizeof(ushort));
    ushort* W1l    = (ushort*)carve(128 * 128 * sizeof(ushort));
    ushort* W2h    = (ushort*)carve(128 * 256 * sizeof(ushort));
    ushort* W2l    = (ushort*)carve(128 * 256 * sizeof(ushort));
    ushort* W3h    = (ushort*)carve(128 * 128 * sizeof(ushort));
    ushort* W3l    = (ushort*)carve(128 * 128 * sizeof(ushort));

    const int* src = edge;
    const int* tgt = edge + NE;

    // prep: weight pre-split (fragment layout) + x hi/lo split
    k_wsplit<128, 64, 0><<<64, 256, 0, stream>>>(Wl1, Wr1, W1h, W1l);
    k_wsplit<256, 128, 0><<<128, 256, 0, stream>>>(Wl2, Wr2, W2h, W2l);
    k_wsplit<128, 128, 1><<<64, 256, 0, stream>>>(Wl3, Wr3, W3h, W3l);
    k_xcast<<<(NN * 8 + 255) / 256, 256, 0, stream>>>(x, xbh, xbl, NN * 8);

    // CSR build
    hipMemsetAsync(counts, 0, NN * sizeof(int), stream);
    k_count<<<(NE + 255) / 256, 256, 0, stream>>>(tgt, counts, rank);
    k_scan1<<<NB_SCAN, 256, 0, stream>>>(counts, bsum);
    k_scan2<<<1, 256, 0, stream>>>(bsum, NB_SCAN);
    k_scan3<<<NB_SCAN, 256, 0, stream>>>(counts, bsum, rowptr);
    k_fill<<<(NE + 255) / 256, 256, 0, stream>>>(src, tgt, rowptr, rank, csr);

    const int MG = (NN + 31) / 32;  // 1563 blocks

    // layer 1: mean1 = mean(x) [pair]; h1 = relu([mean1|x]@[Wl1;Wr1]+b1) [pair]
    k_aggb<64, 1><<<(NN + 3) / 4, 256, 0, stream>>>(xbh, nullptr, 0, nullptr, mn1h, mn1l, rowptr, csr);
    k_mgemm<128, 64, 1, 1><<<MG, 256, 0, stream>>>(mn1h, mn1l, xbh, xbl, W1h, W1l, b1, h1h, h1l, nullptr, nullptr);

    // layer 2: mean2 = mean(h1) [pair]; h2 = relu([mean2|h1]@[Wl2;Wr2]+b2) [pair]
    k_aggb<128, 1><<<(NN + 3) / 4, 256, 0, stream>>>(h1h, nullptr, 0, nullptr, mn2h, mn2l, rowptr, csr);
    k_mgemm<256, 128, 1, 1><<<MG, 256, 0, stream>>>(mn2h, mn2l, h1h, h1l, W2h, W2l, b2, h2h, h2l, nullptr, nullptr);

    // layer 3: p = h2@Wl3 -> pb (bf16); q = h2@Wr3 + b3 (fp32); z = mean(p) + q
    k_mgemm<128, 128, 0, 2><<<MG, 256, 0, stream>>>(h2h, h2l, h2h, h2l, W3h, W3l, b3, nullptr, nullptr, pb, Q);
    k_aggb<64, 0><<<(NN + 3) / 4, 256, 0, stream>>>(pb, Q, 64, Z, nullptr, nullptr, rowptr, csr);

    // decode: out[l] = dot(z[a], z[b])
    k_decode<<<(NL + 31) / 32, 256, 0, stream>>>(eli, Z, out);
}

// Round 15
// 227.347 us; speedup vs baseline: 1.0352x; 1.0352x over previous
//
#include <hip/hip_runtime.h>

#define NN 50000
#define NE 800000
#define NL 200000
#define NB_SCAN 196  // ceil(50000/256)

typedef __attribute__((ext_vector_type(8))) short bf16x8;
typedef __attribute__((ext_vector_type(4))) float f32x4;

__device__ __forceinline__ ushort bf16_rne(float f) {
    union { float f; unsigned u; } v; v.f = f;
    unsigned r = v.u + 0x7FFF + ((v.u >> 16) & 1);
    return (ushort)(r >> 16);
}
__device__ __forceinline__ float bf16_to_f(ushort h) {
    union { unsigned u; float f; } v; v.u = ((unsigned)h) << 16;
    return v.f;
}
__device__ __forceinline__ float lo_f(unsigned u) {
    union { unsigned u; float f; } v; v.u = u << 16;
    return v.f;
}
__device__ __forceinline__ float hi_f(unsigned u) {
    union { unsigned u; float f; } v; v.u = u & 0xffff0000u;
    return v.f;
}

// ---------------- CSR build ----------------

__global__ void k_count(const int* __restrict__ tgt, int* __restrict__ counts,
                        int* __restrict__ rank) {
    int e = blockIdx.x * blockDim.x + threadIdx.x;
    if (e < NE) rank[e] = atomicAdd(&counts[tgt[e]], 1);
}

__global__ void k_scan1(const int* __restrict__ counts, int* __restrict__ bsum) {
    int i = blockIdx.x * 256 + threadIdx.x;
    int v = (i < NN) ? counts[i] : 0;
    #pragma unroll
    for (int off = 32; off; off >>= 1) v += __shfl_down(v, off, 64);
    __shared__ int ws4[4];
    int wave = threadIdx.x >> 6, lane = threadIdx.x & 63;
    if (lane == 0) ws4[wave] = v;
    __syncthreads();
    if (threadIdx.x == 0) bsum[blockIdx.x] = ws4[0] + ws4[1] + ws4[2] + ws4[3];
}

__global__ void k_scan2(int* __restrict__ bsum, int nb) {
    __shared__ int s[256];
    int t = threadIdx.x;
    int v = (t < nb) ? bsum[t] : 0;
    s[t] = v;
    __syncthreads();
    for (int off = 1; off < 256; off <<= 1) {
        int a = (t >= off) ? s[t - off] : 0;
        __syncthreads();
        s[t] += a;
        __syncthreads();
    }
    if (t < nb) bsum[t] = s[t] - v;  // exclusive
}

__global__ void k_scan3(const int* __restrict__ counts, const int* __restrict__ boff,
                        int* __restrict__ rowptr) {
    __shared__ int s[256];
    int t = threadIdx.x;
    int i = blockIdx.x * 256 + t;
    int v = (i < NN) ? counts[i] : 0;
    s[t] = v;
    __syncthreads();
    for (int off = 1; off < 256; off <<= 1) {
        int a = (t >= off) ? s[t - off] : 0;
        __syncthreads();
        s[t] += a;
        __syncthreads();
    }
    int excl = s[t] - v + boff[blockIdx.x];
    if (i < NN) rowptr[i] = excl;
    if (i == NN - 1) rowptr[NN] = excl + v;  // == NE
}

__global__ void k_fill(const int* __restrict__ src, const int* __restrict__ tgt,
                       const int* __restrict__ rowptr, const int* __restrict__ rank,
                       int* __restrict__ csr) {
    int e = blockIdx.x * blockDim.x + threadIdx.x;
    if (e < NE) csr[rowptr[tgt[e]] + rank[e]] = src[e];
}

// ---------------- x -> hi/lo bf16 split ----------------

__global__ void k_xcast(const float* __restrict__ x, ushort* __restrict__ xh,
                        ushort* __restrict__ xl, int n8) {
    int i = blockIdx.x * 256 + threadIdx.x;
    if (i >= n8) return;
    float4 v0 = *(const float4*)&x[i * 8];
    float4 v1 = *(const float4*)&x[i * 8 + 4];
    float av[8] = {v0.x, v0.y, v0.z, v0.w, v1.x, v1.y, v1.z, v1.w};
    ushort h[8], l[8];
    #pragma unroll
    for (int j = 0; j < 8; j++) {
        h[j] = bf16_rne(av[j]);
        l[j] = bf16_rne(av[j] - bf16_to_f(h[j]));
    }
    *(bf16x8*)&xh[i * 8] = *(bf16x8*)h;
    *(bf16x8*)&xl[i * 8] = *(bf16x8*)l;
}

// ---------------- CSR gather-mean aggregation (bf16 gather) ----------------
// OSPLIT=1: write mean as hi/lo bf16 pair. OSPLIT=0: fp32 out (+optional addp).

template <int D, int OSPLIT>
__global__ void k_aggb(const ushort* __restrict__ in,
                       const float* __restrict__ addp, int addStride,
                       float* __restrict__ outF, ushort* __restrict__ outH,
                       ushort* __restrict__ outL,
                       const int* __restrict__ rowptr, const int* __restrict__ csr) {
    constexpr int LPR = D / 8;      // lanes per row: 8 (D=64) or 16 (D=128)
    constexpr int EPW = 64 / LPR;   // edge slots: 8 or 4
    int node = blockIdx.x * 4 + (threadIdx.x >> 6);
    int lane = threadIdx.x & 63;
    if (node >= NN) return;
    int sub = lane / LPR;
    int li  = lane % LPR;           // 8-elem group within row
    int r0 = rowptr[node], r1 = rowptr[node + 1];

    float a[8] = {0.f, 0.f, 0.f, 0.f, 0.f, 0.f, 0.f, 0.f};
    float b[8] = {0.f, 0.f, 0.f, 0.f, 0.f, 0.f, 0.f, 0.f};
    int e0 = r0 + sub;
    int e1 = e0 + EPW;
    int i0 = (e0 < r1) ? csr[e0] : 0;
    int i1 = (e1 < r1) ? csr[e1] : 0;
    while (e1 < r1) {
        int e0n = e0 + 2 * EPW, e1n = e1 + 2 * EPW;
        int i0n = (e0n < r1) ? csr[e0n] : 0;
        int i1n = (e1n < r1) ? csr[e1n] : 0;
        uint4 v0 = *(const uint4*)(in + (size_t)i0 * D + li * 8);
        uint4 v1 = *(const uint4*)(in + (size_t)i1 * D + li * 8);
        a[0] += lo_f(v0.x); a[1] += hi_f(v0.x); a[2] += lo_f(v0.y); a[3] += hi_f(v0.y);
        a[4] += lo_f(v0.z); a[5] += hi_f(v0.z); a[6] += lo_f(v0.w); a[7] += hi_f(v0.w);
        b[0] += lo_f(v1.x); b[1] += hi_f(v1.x); b[2] += lo_f(v1.y); b[3] += hi_f(v1.y);
        b[4] += lo_f(v1.z); b[5] += hi_f(v1.z); b[6] += lo_f(v1.w); b[7] += hi_f(v1.w);
        e0 = e0n; e1 = e1n; i0 = i0n; i1 = i1n;
    }
    if (e0 < r1) {
        uint4 v0 = *(const uint4*)(in + (size_t)i0 * D + li * 8);
        a[0] += lo_f(v0.x); a[1] += hi_f(v0.x); a[2] += lo_f(v0.y); a[3] += hi_f(v0.y);
        a[4] += lo_f(v0.z); a[5] += hi_f(v0.z); a[6] += lo_f(v0.w); a[7] += hi_f(v0.w);
    }
    #pragma unroll
    for (int j = 0; j < 8; j++) a[j] += b[j];
    #pragma unroll
    for (int off = LPR; off < 64; off <<= 1)
        #pragma unroll
        for (int j = 0; j < 8; j++) a[j] += __shfl_xor(a[j], off, 64);
    if (sub == 0) {
        float inv = 1.0f / fmaxf((float)(r1 - r0), 1.0f);
        #pragma unroll
        for (int j = 0; j < 8; j++) a[j] *= inv;
        if constexpr (OSPLIT) {
            ushort h[8], l[8];
            #pragma unroll
            for (int j = 0; j < 8; j++) {
                h[j] = bf16_rne(a[j]);
                l[j] = bf16_rne(a[j] - bf16_to_f(h[j]));
            }
            *(bf16x8*)&outH[(size_t)node * D + li * 8] = *(bf16x8*)h;
            *(bf16x8*)&outL[(size_t)node * D + li * 8] = *(bf16x8*)l;
        } else {
            if (addp) {
                float4 p0 = *(const float4*)&addp[(size_t)node * addStride + li * 8];
                float4 p1 = *(const float4*)&addp[(size_t)node * addStride + li * 8 + 4];
                a[0] += p0.x; a[1] += p0.y; a[2] += p0.z; a[3] += p0.w;
                a[4] += p1.x; a[5] += p1.y; a[6] += p1.z; a[7] += p1.w;
            }
            *(float4*)&outF[(size_t)node * D + li * 8]     = make_float4(a[0], a[1], a[2], a[3]);
            *(float4*)&outF[(size_t)node * D + li * 8 + 4] = make_float4(a[4], a[5], a[6], a[7]);
        }
    }
}

// ---------------- weight pre-split: per-lane MFMA fragment layout ----------------
// frag[chunk][ct][lane][j] -> W[chunk*32 + (lane>>4)*8 + j][ct*16 + (lane&15)].

template <int K, int KA, int NCAT>
__global__ void k_wsplit(const float* __restrict__ W1, const float* __restrict__ W2,
                         ushort* __restrict__ hi, ushort* __restrict__ lo) {
    int id = blockIdx.x * 256 + threadIdx.x;
    if (id >= 128 * K) return;
    int col = id / K, k = id - col * K;
    float v;
    if constexpr (NCAT) {
        v = (col < 64) ? W1[(size_t)k * 64 + col] : W2[(size_t)k * 64 + (col - 64)];
    } else {
        v = (k < KA) ? W1[(size_t)k * 128 + col] : W2[(size_t)(k - KA) * 128 + col];
    }
    ushort h = bf16_rne(v);
    ushort l = bf16_rne(v - bf16_to_f(h));
    int chunk = k >> 5, kk = k & 31;
    int kg4 = kk >> 3, j = kk & 7;
    int ct = col >> 4, lr = col & 15;
    size_t dst = ((size_t)(chunk * 8 + ct) * 64 + kg4 * 16 + lr) * 8 + j;
    hi[dst] = h; lo[dst] = l;
}

// ---------------- MFMA GEMM (pre-split bf16x3 = fp32 accuracy) ----------------
// R13 structure EXACTLY (64-row blocks, 4 waves x 8 col-tiles, W fragments
// double-buffered in regs, A prefetched 1 chunk ahead, no LDS/barriers) with
// ONE change: A arrives PRE-SPLIT hi/lo from producers -> zero conversion
// VALU in the hot loop (was 72 ops/chunk). C = Ah@Wh + Ah@Wl + Al@Wh.
// MFMA layouts (m89): A[j]=A[lr][kg4*8+j], B[j]=B[kg4*8+j][lr], D[j]=C[kg4*4+j][lr].
// OMODE 1: out = hi/lo bf16 pair [n][128] (+bias, +relu).
// OMODE 2: cols 0..63 -> pb bf16 (no bias); cols 64..127 -> q fp32 (+bias).

template <int K, int KA, int RELU, int OMODE>
__launch_bounds__(256, 3)
__global__ void k_mgemm(const ushort* __restrict__ AhiA, const ushort* __restrict__ AloA,
                        const ushort* __restrict__ AhiB, const ushort* __restrict__ AloB,
                        const ushort* __restrict__ Whi, const ushort* __restrict__ Wlo,
                        const float* __restrict__ bias,
                        ushort* __restrict__ outH, ushort* __restrict__ outL,
                        ushort* __restrict__ pbOut, float* __restrict__ qOut) {
    constexpr int KB = K - KA;
    constexpr int NCH = K / 32;   // 4 or 8 (always even)

    int tid = threadIdx.x;
    int wave = tid >> 6, lane = tid & 63;
    int lr  = lane & 15;
    int kg4 = lane >> 4;
    int rbase = blockIdx.x * 64 + wave * 16;
    int row = min(rbase + lr, NN - 1);

    f32x4 acc[8];
    #pragma unroll
    for (int ct = 0; ct < 8; ct++) acc[ct] = (f32x4){0.f, 0.f, 0.f, 0.f};

    const ushort* baseH = Whi + (size_t)lane * 8;
    const ushort* baseL = Wlo + (size_t)lane * 8;

    auto loadApair = [&](int chunk, bf16x8& h, bf16x8& l) {
        int kg2 = chunk * 32 + kg4 * 8;
        if (kg2 < KA) {
            h = *(const bf16x8*)(AhiA + (size_t)row * KA + kg2);
            l = *(const bf16x8*)(AloA + (size_t)row * KA + kg2);
        } else {
            h = *(const bf16x8*)(AhiB + (size_t)row * KB + (kg2 - KA));
            l = *(const bf16x8*)(AloB + (size_t)row * KB + (kg2 - KA));
        }
    };

#define LOADW(c, WH, WL)                                          \
    {                                                             \
        const ushort* ph_ = baseH + (size_t)(c) * 4096;           \
        const ushort* pl_ = baseL + (size_t)(c) * 4096;           \
        _Pragma("unroll")                                         \
        for (int ct_ = 0; ct_ < 8; ct_++) {                       \
            WH[ct_] = *(const bf16x8*)(ph_ + ct_ * 512);          \
            WL[ct_] = *(const bf16x8*)(pl_ + ct_ * 512);          \
        }                                                         \
    }

#define MFMA3(AH, AL, WH, WL)                                     \
    {                                                             \
        _Pragma("unroll")                                         \
        for (int ct_ = 0; ct_ < 8; ct_++) {                       \
            acc[ct_] = __builtin_amdgcn_mfma_f32_16x16x32_bf16(AH, WH[ct_], acc[ct_], 0, 0, 0); \
            acc[ct_] = __builtin_amdgcn_mfma_f32_16x16x32_bf16(AH, WL[ct_], acc[ct_], 0, 0, 0); \
            acc[ct_] = __builtin_amdgcn_mfma_f32_16x16x32_bf16(AL, WH[ct_], acc[ct_], 0, 0, 0); \
        }                                                         \
    }

    bf16x8 whA[8], wlA[8], whB[8], wlB[8];
    bf16x8 ahC, alC, ahN, alN;

    LOADW(0, whA, wlA);
    loadApair(0, ahC, alC);

    #pragma unroll
    for (int c = 0; c < NCH; c += 2) {
        // chunk c (buffer A). Issue chunk c+1 loads into buffer B FIRST.
        if (c + 1 < NCH) { LOADW(c + 1, whB, wlB); loadApair(c + 1, ahN, alN); }
        MFMA3(ahC, alC, whA, wlA);
        // chunk c+1 (buffer B). Issue chunk c+2 loads into buffer A FIRST.
        if (c + 2 < NCH) { LOADW(c + 2, whA, wlA); loadApair(c + 2, ahC, alC); }
        if (c + 1 < NCH) MFMA3(ahN, alN, whB, wlB);
    }
#undef LOADW
#undef MFMA3

    #pragma unroll
    for (int j = 0; j < 4; j++) {
        int n = rbase + kg4 * 4 + j;
        if (n >= NN) continue;
        #pragma unroll
        for (int ct = 0; ct < 8; ct++) {
            if constexpr (OMODE == 1) {
                int c = ct * 16 + lr;
                float v = acc[ct][j] + bias[c];
                if (RELU) v = fmaxf(v, 0.f);
                ushort h = bf16_rne(v);
                outH[(size_t)n * 128 + c] = h;
                outL[(size_t)n * 128 + c] = bf16_rne(v - bf16_to_f(h));
            } else {
                if (ct < 4) {
                    int cc = ct * 16 + lr;
                    pbOut[(size_t)n * 64 + cc] = bf16_rne(acc[ct][j]);
                } else {
                    int cc = (ct - 4) * 16 + lr;
                    qOut[(size_t)n * 64 + cc] = acc[ct][j] + bias[cc];
                }
            }
        }
    }
}

// ---------------- decode ----------------

__global__ void k_decode(const int* __restrict__ eli, const float* __restrict__ z,
                         float* __restrict__ out) {
    int w = blockIdx.x * 4 + (threadIdx.x >> 6);
    int lane = threadIdx.x & 63;
    int sub = lane >> 4, li = lane & 15;
    int e0 = w * 8 + sub;
    int e1 = e0 + 4;
    float s0 = 0.f, s1 = 0.f;
    if (e0 < NL) {
        int a = eli[e0], b = eli[NL + e0];
        float4 va = *(const float4*)&z[(size_t)a * 64 + li * 4];
        float4 vb = *(const float4*)&z[(size_t)b * 64 + li * 4];
        s0 = va.x * vb.x + va.y * vb.y + va.z * vb.z + va.w * vb.w;
    }
    if (e1 < NL) {
        int a = eli[e1], b = eli[NL + e1];
        float4 va = *(const float4*)&z[(size_t)a * 64 + li * 4];
        float4 vb = *(const float4*)&z[(size_t)b * 64 + li * 4];
        s1 = va.x * vb.x + va.y * vb.y + va.z * vb.z + va.w * vb.w;
    }
    #pragma unroll
    for (int off = 1; off < 16; off <<= 1) {
        s0 += __shfl_xor(s0, off, 64);
        s1 += __shfl_xor(s1, off, 64);
    }
    if (li == 0) {
        if (e0 < NL) out[e0] = s0;
        if (e1 < NL) out[e1] = s1;
    }
}

// ---------------- launch ----------------

extern "C" void kernel_launch(void* const* d_in, const int* in_sizes, int n_in,
                              void* d_out, int out_size, void* d_ws, size_t ws_size,
                              hipStream_t stream) {
    const float* x   = (const float*)d_in[0];
    const int*   edge = (const int*)d_in[1];   // [2, NE]
    const int*   eli  = (const int*)d_in[2];   // [2, NL]
    const float* Wl1 = (const float*)d_in[3];
    const float* Wr1 = (const float*)d_in[4];
    const float* b1  = (const float*)d_in[5];
    const float* Wl2 = (const float*)d_in[6];
    const float* Wr2 = (const float*)d_in[7];
    const float* b2  = (const float*)d_in[8];
    const float* Wl3 = (const float*)d_in[9];
    const float* Wr3 = (const float*)d_in[10];
    const float* b3  = (const float*)d_in[11];
    float* out = (float*)d_out;

    char* w = (char*)d_ws;
    auto carve = [&](size_t bytes) {
        char* p = w;
        w += (bytes + 255) & ~(size_t)255;
        return p;
    };
    int*    rowptr = (int*)carve((NN + 1) * sizeof(int));
    int*    counts = (int*)carve(NN * sizeof(int));
    int*    rank   = (int*)carve(NE * sizeof(int));
    int*    csr    = (int*)carve(NE * sizeof(int));
    int*    bsum   = (int*)carve(256 * sizeof(int));
    float*  Z      = (float*)carve((size_t)NN * 64 * sizeof(float));    // z
    float*  Q      = (float*)carve((size_t)NN * 64 * sizeof(float));    // q
    ushort* xbh    = (ushort*)carve((size_t)NN * 64 * sizeof(ushort));
    ushort* xbl    = (ushort*)carve((size_t)NN * 64 * sizeof(ushort));
    ushort* mn1h   = (ushort*)carve((size_t)NN * 64 * sizeof(ushort));
    ushort* mn1l   = (ushort*)carve((size_t)NN * 64 * sizeof(ushort));
    ushort* h1h    = (ushort*)carve((size_t)NN * 128 * sizeof(ushort));
    ushort* h1l    = (ushort*)carve((size_t)NN * 128 * sizeof(ushort));
    ushort* mn2h   = (ushort*)carve((size_t)NN * 128 * sizeof(ushort));
    ushort* mn2l   = (ushort*)carve((size_t)NN * 128 * sizeof(ushort));
    ushort* h2h    = (ushort*)carve((size_t)NN * 128 * sizeof(ushort));
    ushort* h2l    = (ushort*)carve((size_t)NN * 128 * sizeof(ushort));
    ushort* pb     = (ushort*)carve((size_t)NN * 64 * sizeof(ushort));
    ushort* W1h    = (ushort*)carve(128 * 128 * sizeof(ushort));
    ushort* W1l    = (ushort*)carve(128 * 128 * sizeof(ushort));
    ushort* W2h    = (ushort*)carve(128 * 256 * sizeof(ushort));
    ushort* W2l    = (ushort*)carve(128 * 256 * sizeof(ushort));
    ushort* W3h    = (ushort*)carve(128 * 128 * sizeof(ushort));
    ushort* W3l    = (ushort*)carve(128 * 128 * sizeof(ushort));

    const int* src = edge;
    const int* tgt = edge + NE;

    // prep: weight pre-split (fragment layout) + x hi/lo split
    k_wsplit<128, 64, 0><<<64, 256, 0, stream>>>(Wl1, Wr1, W1h, W1l);
    k_wsplit<256, 128, 0><<<128, 256, 0, stream>>>(Wl2, Wr2, W2h, W2l);
    k_wsplit<128, 128, 1><<<64, 256, 0, stream>>>(Wl3, Wr3, W3h, W3l);
    k_xcast<<<(NN * 8 + 255) / 256, 256, 0, stream>>>(x, xbh, xbl, NN * 8);

    // CSR build
    hipMemsetAsync(counts, 0, NN * sizeof(int), stream);
    k_count<<<(NE + 255) / 256, 256, 0, stream>>>(tgt, counts, rank);
    k_scan1<<<NB_SCAN, 256, 0, stream>>>(counts, bsum);
    k_scan2<<<1, 256, 0, stream>>>(bsum, NB_SCAN);
    k_scan3<<<NB_SCAN, 256, 0, stream>>>(counts, bsum, rowptr);
    k_fill<<<(NE + 255) / 256, 256, 0, stream>>>(src, tgt, rowptr, rank, csr);

    const int MG = (NN + 63) / 64;  // 782 blocks (R13 tiling)

    // layer 1: mean1 = mean(x) [pair]; h1 = relu([mean1|x]@[Wl1;Wr1]+b1) [pair]
    k_aggb<64, 1><<<(NN + 3) / 4, 256, 0, stream>>>(xbh, nullptr, 0, nullptr, mn1h, mn1l, rowptr, csr);
    k_mgemm<128, 64, 1, 1><<<MG, 256, 0, stream>>>(mn1h, mn1l, xbh, xbl, W1h, W1l, b1, h1h, h1l, nullptr, nullptr);

    // layer 2: mean2 = mean(h1) [pair]; h2 = relu([mean2|h1]@[Wl2;Wr2]+b2) [pair]
    k_aggb<128, 1><<<(NN + 3) / 4, 256, 0, stream>>>(h1h, nullptr, 0, nullptr, mn2h, mn2l, rowptr, csr);
    k_mgemm<256, 128, 1, 1><<<MG, 256, 0, stream>>>(mn2h, mn2l, h1h, h1l, W2h, W2l, b2, h2h, h2l, nullptr, nullptr);

    // layer 3: p = h2@Wl3 -> pb (bf16); q = h2@Wr3 + b3 (fp32); z = mean(p) + q
    k_mgemm<128, 128, 0, 2><<<MG, 256, 0, stream>>>(h2h, h2l, h2h, h2l, W3h, W3l, b3, nullptr, nullptr, pb, Q);
    k_aggb<64, 0><<<(NN + 3) / 4, 256, 0, stream>>>(pb, Q, 64, Z, nullptr, nullptr, rowptr, csr);

    // decode: out[l] = dot(z[a], z[b])
    k_decode<<<(NL + 31) / 32, 256, 0, stream>>>(eli, Z, out);
}

// Round 16
// 212.181 us; speedup vs baseline: 1.1092x; 1.0715x over previous
//
#include <hip/hip_runtime.h>

#define NN 50000
#define NE 800000
#define NL 200000
#define NB_SCAN 196  // ceil(50000/256)

typedef __attribute__((ext_vector_type(8))) short bf16x8;
typedef __attribute__((ext_vector_type(4))) float f32x4;

__device__ __forceinline__ ushort bf16_rne(float f) {
    union { float f; unsigned u; } v; v.f = f;
    unsigned r = v.u + 0x7FFF + ((v.u >> 16) & 1);
    return (ushort)(r >> 16);
}
__device__ __forceinline__ float bf16_to_f(ushort h) {
    union { unsigned u; float f; } v; v.u = ((unsigned)h) << 16;
    return v.f;
}
__device__ __forceinline__ float lo_f(unsigned u) {
    union { unsigned u; float f; } v; v.u = u << 16;
    return v.f;
}
__device__ __forceinline__ float hi_f(unsigned u) {
    union { unsigned u; float f; } v; v.u = u & 0xffff0000u;
    return v.f;
}

// ---------------- CSR build ----------------

__global__ void k_count(const int* __restrict__ tgt, int* __restrict__ counts,
                        int* __restrict__ rank) {
    int e = blockIdx.x * blockDim.x + threadIdx.x;
    if (e < NE) rank[e] = atomicAdd(&counts[tgt[e]], 1);
}

__global__ void k_scan1(const int* __restrict__ counts, int* __restrict__ bsum) {
    int i = blockIdx.x * 256 + threadIdx.x;
    int v = (i < NN) ? counts[i] : 0;
    #pragma unroll
    for (int off = 32; off; off >>= 1) v += __shfl_down(v, off, 64);
    __shared__ int ws4[4];
    int wave = threadIdx.x >> 6, lane = threadIdx.x & 63;
    if (lane == 0) ws4[wave] = v;
    __syncthreads();
    if (threadIdx.x == 0) bsum[blockIdx.x] = ws4[0] + ws4[1] + ws4[2] + ws4[3];
}

__global__ void k_scan2(int* __restrict__ bsum, int nb) {
    __shared__ int s[256];
    int t = threadIdx.x;
    int v = (t < nb) ? bsum[t] : 0;
    s[t] = v;
    __syncthreads();
    for (int off = 1; off < 256; off <<= 1) {
        int a = (t >= off) ? s[t - off] : 0;
        __syncthreads();
        s[t] += a;
        __syncthreads();
    }
    if (t < nb) bsum[t] = s[t] - v;  // exclusive
}

__global__ void k_scan3(const int* __restrict__ counts, const int* __restrict__ boff,
                        int* __restrict__ rowptr) {
    __shared__ int s[256];
    int t = threadIdx.x;
    int i = blockIdx.x * 256 + t;
    int v = (i < NN) ? counts[i] : 0;
    s[t] = v;
    __syncthreads();
    for (int off = 1; off < 256; off <<= 1) {
        int a = (t >= off) ? s[t - off] : 0;
        __syncthreads();
        s[t] += a;
        __syncthreads();
    }
    int excl = s[t] - v + boff[blockIdx.x];
    if (i < NN) rowptr[i] = excl;
    if (i == NN - 1) rowptr[NN] = excl + v;  // == NE
}

__global__ void k_fill(const int* __restrict__ src, const int* __restrict__ tgt,
                       const int* __restrict__ rowptr, const int* __restrict__ rank,
                       int* __restrict__ csr) {
    int e = blockIdx.x * blockDim.x + threadIdx.x;
    if (e < NE) csr[rowptr[tgt[e]] + rank[e]] = src[e];
}

// ---------------- x -> bf16 cast ----------------

__global__ void k_xcast(const float* __restrict__ x, ushort* __restrict__ xb, int n8) {
    int i = blockIdx.x * 256 + threadIdx.x;
    if (i >= n8) return;
    float4 v0 = *(const float4*)&x[i * 8];
    float4 v1 = *(const float4*)&x[i * 8 + 4];
    ushort h[8] = {bf16_rne(v0.x), bf16_rne(v0.y), bf16_rne(v0.z), bf16_rne(v0.w),
                   bf16_rne(v1.x), bf16_rne(v1.y), bf16_rne(v1.z), bf16_rne(v1.w)};
    *(bf16x8*)&xb[i * 8] = *(bf16x8*)h;
}

// ---------------- CSR gather-mean aggregation (bf16 gather) ----------------

template <int D>
__global__ void k_aggb(const ushort* __restrict__ in,
                       const float* __restrict__ addp, int addStride,
                       float* __restrict__ out, int outStride,
                       const int* __restrict__ rowptr, const int* __restrict__ csr) {
    constexpr int LPR = D / 8;      // lanes per row: 8 (D=64) or 16 (D=128)
    constexpr int EPW = 64 / LPR;   // edge slots: 8 or 4
    int node = blockIdx.x * 4 + (threadIdx.x >> 6);
    int lane = threadIdx.x & 63;
    if (node >= NN) return;
    int sub = lane / LPR;
    int li  = lane % LPR;           // 8-elem group within row
    int r0 = rowptr[node], r1 = rowptr[node + 1];

    float a[8] = {0.f, 0.f, 0.f, 0.f, 0.f, 0.f, 0.f, 0.f};
    float b[8] = {0.f, 0.f, 0.f, 0.f, 0.f, 0.f, 0.f, 0.f};
    int e0 = r0 + sub;
    int e1 = e0 + EPW;
    int i0 = (e0 < r1) ? csr[e0] : 0;
    int i1 = (e1 < r1) ? csr[e1] : 0;
    while (e1 < r1) {
        int e0n = e0 + 2 * EPW, e1n = e1 + 2 * EPW;
        int i0n = (e0n < r1) ? csr[e0n] : 0;
        int i1n = (e1n < r1) ? csr[e1n] : 0;
        uint4 v0 = *(const uint4*)(in + (size_t)i0 * D + li * 8);
        uint4 v1 = *(const uint4*)(in + (size_t)i1 * D + li * 8);
        a[0] += lo_f(v0.x); a[1] += hi_f(v0.x); a[2] += lo_f(v0.y); a[3] += hi_f(v0.y);
        a[4] += lo_f(v0.z); a[5] += hi_f(v0.z); a[6] += lo_f(v0.w); a[7] += hi_f(v0.w);
        b[0] += lo_f(v1.x); b[1] += hi_f(v1.x); b[2] += lo_f(v1.y); b[3] += hi_f(v1.y);
        b[4] += lo_f(v1.z); b[5] += hi_f(v1.z); b[6] += lo_f(v1.w); b[7] += hi_f(v1.w);
        e0 = e0n; e1 = e1n; i0 = i0n; i1 = i1n;
    }
    if (e0 < r1) {
        uint4 v0 = *(const uint4*)(in + (size_t)i0 * D + li * 8);
        a[0] += lo_f(v0.x); a[1] += hi_f(v0.x); a[2] += lo_f(v0.y); a[3] += hi_f(v0.y);
        a[4] += lo_f(v0.z); a[5] += hi_f(v0.z); a[6] += lo_f(v0.w); a[7] += hi_f(v0.w);
    }
    #pragma unroll
    for (int j = 0; j < 8; j++) a[j] += b[j];
    #pragma unroll
    for (int off = LPR; off < 64; off <<= 1)
        #pragma unroll
        for (int j = 0; j < 8; j++) a[j] += __shfl_xor(a[j], off, 64);
    if (sub == 0) {
        float inv = 1.0f / fmaxf((float)(r1 - r0), 1.0f);
        #pragma unroll
        for (int j = 0; j < 8; j++) a[j] *= inv;
        if (addp) {
            float4 p0 = *(const float4*)&addp[(size_t)node * addStride + li * 8];
            float4 p1 = *(const float4*)&addp[(size_t)node * addStride + li * 8 + 4];
            a[0] += p0.x; a[1] += p0.y; a[2] += p0.z; a[3] += p0.w;
            a[4] += p1.x; a[5] += p1.y; a[6] += p1.z; a[7] += p1.w;
        }
        *(float4*)&out[(size_t)node * outStride + li * 8]     = make_float4(a[0], a[1], a[2], a[3]);
        *(float4*)&out[(size_t)node * outStride + li * 8 + 4] = make_float4(a[4], a[5], a[6], a[7]);
    }
}

// ---------------- weight pre-split: per-lane MFMA fragment layout (hi only) ----------------
// frag[chunk][ct][lane][j] -> W[chunk*32 + (lane>>4)*8 + j][ct*16 + (lane&15)].

template <int K, int KA, int NCAT>
__global__ void k_wsplit(const float* __restrict__ W1, const float* __restrict__ W2,
                         ushort* __restrict__ hi) {
    int id = blockIdx.x * 256 + threadIdx.x;
    if (id >= 128 * K) return;
    int col = id / K, k = id - col * K;
    float v;
    if constexpr (NCAT) {
        v = (col < 64) ? W1[(size_t)k * 64 + col] : W2[(size_t)k * 64 + (col - 64)];
    } else {
        v = (k < KA) ? W1[(size_t)k * 128 + col] : W2[(size_t)(k - KA) * 128 + col];
    }
    int chunk = k >> 5, kk = k & 31;
    int kg4 = kk >> 3, j = kk & 7;
    int ct = col >> 4, lr = col & 15;
    size_t dst = ((size_t)(chunk * 8 + ct) * 64 + kg4 * 16 + lr) * 8 + j;
    hi[dst] = bf16_rne(v);
}

// ---------------- MFMA GEMM (A split hi/lo, W bf16: C = (Ah+Al)@Wh) ----------------
// R13 structure EXACTLY (64-row blocks, 4 waves x 8 col-tiles, W fragments
// double-buffered in regs, A fp32 loaded+split in-kernel, prefetch 1 chunk,
// no LDS/barriers) with ONE change: W-lo term dropped -> 8 W-loads/chunk
// (was 16), 16 MFMA/chunk (was 24), W dbuf 64 VGPR (was 128).
// A stays fp32-effective (hi+lo); only W is bf16-rounded (~2^-9 rel).
// MFMA layouts (m89): A[j]=A[lr][kg4*8+j], B[j]=B[kg4*8+j][lr], D[j]=C[kg4*4+j][lr].
// OMODE 1: out = fp32 [n][128] (+bias,+relu) + bf16 copy (BFOUT=1 full / 2 cols 0..63).

template <int K, int KA, int NCAT, int RELU, int BFOUT>
__launch_bounds__(256, 3)
__global__ void k_mgemm(const float* __restrict__ inA, const float* __restrict__ inB,
                        const ushort* __restrict__ Whi,
                        const float* __restrict__ bias, float* __restrict__ out,
                        ushort* __restrict__ bfout) {
    constexpr int KB = K - KA;
    constexpr int NCH = K / 32;   // 4 or 8 (always even)

    int tid = threadIdx.x;
    int wave = tid >> 6, lane = tid & 63;
    int lr  = lane & 15;
    int kg4 = lane >> 4;
    int rbase = blockIdx.x * 64 + wave * 16;
    int row = min(rbase + lr, NN - 1);

    f32x4 acc[8];
    #pragma unroll
    for (int ct = 0; ct < 8; ct++) acc[ct] = (f32x4){0.f, 0.f, 0.f, 0.f};

    const ushort* baseH = Whi + (size_t)lane * 8;

    auto loadA = [&](int chunk, float4& v0, float4& v1) {
        int kg2 = chunk * 32 + kg4 * 8;
        if constexpr (NCAT) {
            v0 = *(const float4*)&inA[(size_t)row * K + kg2];
            v1 = *(const float4*)&inA[(size_t)row * K + kg2 + 4];
        } else {
            if (kg2 < KA) v0 = *(const float4*)&inA[(size_t)row * KA + kg2];
            else          v0 = *(const float4*)&inB[(size_t)row * KB + (kg2 - KA)];
            if (kg2 + 4 < KA) v1 = *(const float4*)&inA[(size_t)row * KA + kg2 + 4];
            else              v1 = *(const float4*)&inB[(size_t)row * KB + (kg2 + 4 - KA)];
        }
    };

#define LOADW(c, WH)                                              \
    {                                                             \
        const ushort* ph_ = baseH + (size_t)(c) * 4096;           \
        _Pragma("unroll")                                         \
        for (int ct_ = 0; ct_ < 8; ct_++) {                       \
            WH[ct_] = *(const bf16x8*)(ph_ + ct_ * 512);          \
        }                                                         \
    }

#define CONVA(V0, V1, AH, AL)                                     \
    {                                                             \
        float av_[8] = {V0.x, V0.y, V0.z, V0.w, V1.x, V1.y, V1.z, V1.w}; \
        _Pragma("unroll")                                         \
        for (int j_ = 0; j_ < 8; j_++) {                          \
            ushort h_ = bf16_rne(av_[j_]);                        \
            ushort l_ = bf16_rne(av_[j_] - bf16_to_f(h_));        \
            AH[j_] = (short)h_;                                   \
            AL[j_] = (short)l_;                                   \
        }                                                         \
    }

#define MFMA2(AH, AL, WH)                                         \
    {                                                             \
        _Pragma("unroll")                                         \
        for (int ct_ = 0; ct_ < 8; ct_++) {                       \
            acc[ct_] = __builtin_amdgcn_mfma_f32_16x16x32_bf16(AH, WH[ct_], acc[ct_], 0, 0, 0); \
            acc[ct_] = __builtin_amdgcn_mfma_f32_16x16x32_bf16(AL, WH[ct_], acc[ct_], 0, 0, 0); \
        }                                                         \
    }

    bf16x8 whA[8], whB[8];
    float4 aC0, aC1, aN0, aN1;

    LOADW(0, whA);
    loadA(0, aC0, aC1);

    #pragma unroll
    for (int c = 0; c < NCH; c += 2) {
        // chunk c (buffer A). Issue chunk c+1 loads into buffer B FIRST.
        if (c + 1 < NCH) { LOADW(c + 1, whB); loadA(c + 1, aN0, aN1); }
        {
            bf16x8 ah, al;
            CONVA(aC0, aC1, ah, al);
            MFMA2(ah, al, whA);
        }
        // chunk c+1 (buffer B). Issue chunk c+2 loads into buffer A FIRST.
        if (c + 2 < NCH) { LOADW(c + 2, whA); loadA(c + 2, aC0, aC1); }
        if (c + 1 < NCH) {
            bf16x8 ah, al;
            CONVA(aN0, aN1, ah, al);
            MFMA2(ah, al, whB);
        }
    }
#undef LOADW
#undef CONVA
#undef MFMA2

    float bc[8];
    #pragma unroll
    for (int ct = 0; ct < 8; ct++) {
        int c = ct * 16 + lr;
        if constexpr (NCAT) bc[ct] = (c < 64) ? 0.f : bias[c - 64];
        else bc[ct] = bias[c];
    }
    #pragma unroll
    for (int j = 0; j < 4; j++) {
        int n = rbase + kg4 * 4 + j;
        if (n < NN) {
            float* orow = &out[(size_t)n * 128 + lr];
            #pragma unroll
            for (int ct = 0; ct < 8; ct++) {
                float v = acc[ct][j] + bc[ct];
                if (RELU) v = fmaxf(v, 0.f);
                orow[ct * 16] = v;
                if constexpr (BFOUT == 1) bfout[(size_t)n * 128 + ct * 16 + lr] = bf16_rne(v);
                if constexpr (BFOUT == 2) { if (ct < 4) bfout[(size_t)n * 64 + ct * 16 + lr] = bf16_rne(v); }
            }
        }
    }
}

// ---------------- decode ----------------

__global__ void k_decode(const int* __restrict__ eli, const float* __restrict__ z,
                         float* __restrict__ out) {
    int w = blockIdx.x * 4 + (threadIdx.x >> 6);
    int lane = threadIdx.x & 63;
    int sub = lane >> 4, li = lane & 15;
    int e0 = w * 8 + sub;
    int e1 = e0 + 4;
    float s0 = 0.f, s1 = 0.f;
    if (e0 < NL) {
        int a = eli[e0], b = eli[NL + e0];
        float4 va = *(const float4*)&z[(size_t)a * 64 + li * 4];
        float4 vb = *(const float4*)&z[(size_t)b * 64 + li * 4];
        s0 = va.x * vb.x + va.y * vb.y + va.z * vb.z + va.w * vb.w;
    }
    if (e1 < NL) {
        int a = eli[e1], b = eli[NL + e1];
        float4 va = *(const float4*)&z[(size_t)a * 64 + li * 4];
        float4 vb = *(const float4*)&z[(size_t)b * 64 + li * 4];
        s1 = va.x * vb.x + va.y * vb.y + va.z * vb.z + va.w * vb.w;
    }
    #pragma unroll
    for (int off = 1; off < 16; off <<= 1) {
        s0 += __shfl_xor(s0, off, 64);
        s1 += __shfl_xor(s1, off, 64);
    }
    if (li == 0) {
        if (e0 < NL) out[e0] = s0;
        if (e1 < NL) out[e1] = s1;
    }
}

// ---------------- launch ----------------

extern "C" void kernel_launch(void* const* d_in, const int* in_sizes, int n_in,
                              void* d_out, int out_size, void* d_ws, size_t ws_size,
                              hipStream_t stream) {
    const float* x   = (const float*)d_in[0];
    const int*   edge = (const int*)d_in[1];   // [2, NE]
    const int*   eli  = (const int*)d_in[2];   // [2, NL]
    const float* Wl1 = (const float*)d_in[3];
    const float* Wr1 = (const float*)d_in[4];
    const float* b1  = (const float*)d_in[5];
    const float* Wl2 = (const float*)d_in[6];
    const float* Wr2 = (const float*)d_in[7];
    const float* b2  = (const float*)d_in[8];
    const float* Wl3 = (const float*)d_in[9];
    const float* Wr3 = (const float*)d_in[10];
    const float* b3  = (const float*)d_in[11];
    float* out = (float*)d_out;

    char* w = (char*)d_ws;
    auto carve = [&](size_t bytes) {
        char* p = w;
        w += (bytes + 255) & ~(size_t)255;
        return p;
    };
    int*    rowptr = (int*)carve((NN + 1) * sizeof(int));
    int*    counts = (int*)carve(NN * sizeof(int));
    int*    rank   = (int*)carve(NE * sizeof(int));
    int*    csr    = (int*)carve(NE * sizeof(int));
    int*    bsum   = (int*)carve(256 * sizeof(int));
    float*  M      = (float*)carve((size_t)NN * 64 * sizeof(float));   // mean1, later z
    float*  A      = (float*)carve((size_t)NN * 128 * sizeof(float));  // h1
    float*  B      = (float*)carve((size_t)NN * 128 * sizeof(float));  // mean2, later pq
    float*  C      = (float*)carve((size_t)NN * 128 * sizeof(float));  // h2
    ushort* xb     = (ushort*)carve((size_t)NN * 64 * sizeof(ushort));  // bf16 x
    ushort* h1b    = (ushort*)carve((size_t)NN * 128 * sizeof(ushort)); // bf16 h1
    ushort* pb     = (ushort*)carve((size_t)NN * 64 * sizeof(ushort));  // bf16 p
    ushort* W1h    = (ushort*)carve(128 * 128 * sizeof(ushort));
    ushort* W2h    = (ushort*)carve(128 * 256 * sizeof(ushort));
    ushort* W3h    = (ushort*)carve(128 * 128 * sizeof(ushort));

    const int* src = edge;
    const int* tgt = edge + NE;

    // prep: weight bf16 fragment layout + x bf16 cast
    k_wsplit<128, 64, 0><<<64, 256, 0, stream>>>(Wl1, Wr1, W1h);
    k_wsplit<256, 128, 0><<<128, 256, 0, stream>>>(Wl2, Wr2, W2h);
    k_wsplit<128, 128, 1><<<64, 256, 0, stream>>>(Wl3, Wr3, W3h);
    k_xcast<<<(NN * 8 + 255) / 256, 256, 0, stream>>>(x, xb, NN * 8);

    // CSR build
    hipMemsetAsync(counts, 0, NN * sizeof(int), stream);
    k_count<<<(NE + 255) / 256, 256, 0, stream>>>(tgt, counts, rank);
    k_scan1<<<NB_SCAN, 256, 0, stream>>>(counts, bsum);
    k_scan2<<<1, 256, 0, stream>>>(bsum, NB_SCAN);
    k_scan3<<<NB_SCAN, 256, 0, stream>>>(counts, bsum, rowptr);
    k_fill<<<(NE + 255) / 256, 256, 0, stream>>>(src, tgt, rowptr, rank, csr);

    const int MG = (NN + 63) / 64;  // 782 blocks (R13 tiling)

    // layer 1: mean1 = mean(x); h1 = relu([mean1|x]@[Wl1;Wr1]+b1)  (+h1 bf16 copy)
    k_aggb<64><<<(NN + 3) / 4, 256, 0, stream>>>(xb, nullptr, 0, M, 64, rowptr, csr);
    k_mgemm<128, 64, 0, 1, 1><<<MG, 256, 0, stream>>>(M, x, W1h, b1, A, h1b);

    // layer 2: mean2 = mean(h1); h2 = relu([mean2|h1]@[Wl2;Wr2]+b2)
    k_aggb<128><<<(NN + 3) / 4, 256, 0, stream>>>(h1b, nullptr, 0, B, 128, rowptr, csr);
    k_mgemm<256, 128, 0, 1, 0><<<MG, 256, 0, stream>>>(B, A, W2h, b2, C, nullptr);

    // layer 3: pq = h2 @ [Wl3 | Wr3] (+p bf16 copy); z = mean(p) + q
    k_mgemm<128, 128, 1, 0, 2><<<MG, 256, 0, stream>>>(C, nullptr, W3h, b3, B, pb);
    k_aggb<64><<<(NN + 3) / 4, 256, 0, stream>>>(pb, B + 64, 128, M, 64, rowptr, csr);

    // decode: out[l] = dot(z[a], z[b])
    k_decode<<<(NL + 31) / 32, 256, 0, stream>>>(eli, M, out);
}

// Round 17
// 208.970 us; speedup vs baseline: 1.1263x; 1.0154x over previous
//
#include <hip/hip_runtime.h>

#define NN 50000
#define NE 800000
#define NL 200000
#define NB_SCAN 196  // ceil(50000/256)

typedef __attribute__((ext_vector_type(8))) short bf16x8;
typedef __attribute__((ext_vector_type(4))) float f32x4;

__device__ __forceinline__ ushort bf16_rne(float f) {
    union { float f; unsigned u; } v; v.f = f;
    unsigned r = v.u + 0x7FFF + ((v.u >> 16) & 1);
    return (ushort)(r >> 16);
}
__device__ __forceinline__ float bf16_to_f(ushort h) {
    union { unsigned u; float f; } v; v.u = ((unsigned)h) << 16;
    return v.f;
}
__device__ __forceinline__ float lo_f(unsigned u) {
    union { unsigned u; float f; } v; v.u = u << 16;
    return v.f;
}
__device__ __forceinline__ float hi_f(unsigned u) {
    union { unsigned u; float f; } v; v.u = u & 0xffff0000u;
    return v.f;
}

// ---------------- CSR build ----------------

__global__ void k_count(const int* __restrict__ tgt, int* __restrict__ counts,
                        int* __restrict__ rank) {
    int e = blockIdx.x * blockDim.x + threadIdx.x;
    if (e < NE) rank[e] = atomicAdd(&counts[tgt[e]], 1);
}

__global__ void k_scan1(const int* __restrict__ counts, int* __restrict__ bsum) {
    int i = blockIdx.x * 256 + threadIdx.x;
    int v = (i < NN) ? counts[i] : 0;
    #pragma unroll
    for (int off = 32; off; off >>= 1) v += __shfl_down(v, off, 64);
    __shared__ int ws4[4];
    int wave = threadIdx.x >> 6, lane = threadIdx.x & 63;
    if (lane == 0) ws4[wave] = v;
    __syncthreads();
    if (threadIdx.x == 0) bsum[blockIdx.x] = ws4[0] + ws4[1] + ws4[2] + ws4[3];
}

__global__ void k_scan2(int* __restrict__ bsum, int nb) {
    __shared__ int s[256];
    int t = threadIdx.x;
    int v = (t < nb) ? bsum[t] : 0;
    s[t] = v;
    __syncthreads();
    for (int off = 1; off < 256; off <<= 1) {
        int a = (t >= off) ? s[t - off] : 0;
        __syncthreads();
        s[t] += a;
        __syncthreads();
    }
    if (t < nb) bsum[t] = s[t] - v;  // exclusive
}

__global__ void k_scan3(const int* __restrict__ counts, const int* __restrict__ boff,
                        int* __restrict__ rowptr) {
    __shared__ int s[256];
    int t = threadIdx.x;
    int i = blockIdx.x * 256 + t;
    int v = (i < NN) ? counts[i] : 0;
    s[t] = v;
    __syncthreads();
    for (int off = 1; off < 256; off <<= 1) {
        int a = (t >= off) ? s[t - off] : 0;
        __syncthreads();
        s[t] += a;
        __syncthreads();
    }
    int excl = s[t] - v + boff[blockIdx.x];
    if (i < NN) rowptr[i] = excl;
    if (i == NN - 1) rowptr[NN] = excl + v;  // == NE
}

__global__ void k_fill(const int* __restrict__ src, const int* __restrict__ tgt,
                       const int* __restrict__ rowptr, const int* __restrict__ rank,
                       int* __restrict__ csr) {
    int e = blockIdx.x * blockDim.x + threadIdx.x;
    if (e < NE) csr[rowptr[tgt[e]] + rank[e]] = src[e];
}

// ---------------- x -> bf16 cast ----------------

__global__ void k_xcast(const float* __restrict__ x, ushort* __restrict__ xb, int n8) {
    int i = blockIdx.x * 256 + threadIdx.x;
    if (i >= n8) return;
    float4 v0 = *(const float4*)&x[i * 8];
    float4 v1 = *(const float4*)&x[i * 8 + 4];
    ushort h[8] = {bf16_rne(v0.x), bf16_rne(v0.y), bf16_rne(v0.z), bf16_rne(v0.w),
                   bf16_rne(v1.x), bf16_rne(v1.y), bf16_rne(v1.z), bf16_rne(v1.w)};
    *(bf16x8*)&xb[i * 8] = *(bf16x8*)h;
}

// ---------------- CSR gather-mean aggregation (bf16 gather) ----------------

template <int D>
__global__ void k_aggb(const ushort* __restrict__ in,
                       const float* __restrict__ addp, int addStride,
                       float* __restrict__ out, int outStride,
                       const int* __restrict__ rowptr, const int* __restrict__ csr) {
    constexpr int LPR = D / 8;      // lanes per row: 8 (D=64) or 16 (D=128)
    constexpr int EPW = 64 / LPR;   // edge slots: 8 or 4
    int node = blockIdx.x * 4 + (threadIdx.x >> 6);
    int lane = threadIdx.x & 63;
    if (node >= NN) return;
    int sub = lane / LPR;
    int li  = lane % LPR;           // 8-elem group within row
    int r0 = rowptr[node], r1 = rowptr[node + 1];

    float a[8] = {0.f, 0.f, 0.f, 0.f, 0.f, 0.f, 0.f, 0.f};
    float b[8] = {0.f, 0.f, 0.f, 0.f, 0.f, 0.f, 0.f, 0.f};
    int e0 = r0 + sub;
    int e1 = e0 + EPW;
    int i0 = (e0 < r1) ? csr[e0] : 0;
    int i1 = (e1 < r1) ? csr[e1] : 0;
    while (e1 < r1) {
        int e0n = e0 + 2 * EPW, e1n = e1 + 2 * EPW;
        int i0n = (e0n < r1) ? csr[e0n] : 0;
        int i1n = (e1n < r1) ? csr[e1n] : 0;
        uint4 v0 = *(const uint4*)(in + (size_t)i0 * D + li * 8);
        uint4 v1 = *(const uint4*)(in + (size_t)i1 * D + li * 8);
        a[0] += lo_f(v0.x); a[1] += hi_f(v0.x); a[2] += lo_f(v0.y); a[3] += hi_f(v0.y);
        a[4] += lo_f(v0.z); a[5] += hi_f(v0.z); a[6] += lo_f(v0.w); a[7] += hi_f(v0.w);
        b[0] += lo_f(v1.x); b[1] += hi_f(v1.x); b[2] += lo_f(v1.y); b[3] += hi_f(v1.y);
        b[4] += lo_f(v1.z); b[5] += hi_f(v1.z); b[6] += lo_f(v1.w); b[7] += hi_f(v1.w);
        e0 = e0n; e1 = e1n; i0 = i0n; i1 = i1n;
    }
    if (e0 < r1) {
        uint4 v0 = *(const uint4*)(in + (size_t)i0 * D + li * 8);
        a[0] += lo_f(v0.x); a[1] += hi_f(v0.x); a[2] += lo_f(v0.y); a[3] += hi_f(v0.y);
        a[4] += lo_f(v0.z); a[5] += hi_f(v0.z); a[6] += lo_f(v0.w); a[7] += hi_f(v0.w);
    }
    #pragma unroll
    for (int j = 0; j < 8; j++) a[j] += b[j];
    #pragma unroll
    for (int off = LPR; off < 64; off <<= 1)
        #pragma unroll
        for (int j = 0; j < 8; j++) a[j] += __shfl_xor(a[j], off, 64);
    if (sub == 0) {
        float inv = 1.0f / fmaxf((float)(r1 - r0), 1.0f);
        #pragma unroll
        for (int j = 0; j < 8; j++) a[j] *= inv;
        if (addp) {
            float4 p0 = *(const float4*)&addp[(size_t)node * addStride + li * 8];
            float4 p1 = *(const float4*)&addp[(size_t)node * addStride + li * 8 + 4];
            a[0] += p0.x; a[1] += p0.y; a[2] += p0.z; a[3] += p0.w;
            a[4] += p1.x; a[5] += p1.y; a[6] += p1.z; a[7] += p1.w;
        }
        *(float4*)&out[(size_t)node * outStride + li * 8]     = make_float4(a[0], a[1], a[2], a[3]);
        *(float4*)&out[(size_t)node * outStride + li * 8 + 4] = make_float4(a[4], a[5], a[6], a[7]);
    }
}

// ---------------- weight fragment layout (bf16, hi only) ----------------
// frag[chunk][ct][lane][j] -> W[chunk*32 + (lane>>4)*8 + j][ct*16 + (lane&15)].

template <int K, int KA, int NCAT>
__global__ void k_wsplit(const float* __restrict__ W1, const float* __restrict__ W2,
                         ushort* __restrict__ hi) {
    int id = blockIdx.x * 256 + threadIdx.x;
    if (id >= 128 * K) return;
    int col = id / K, k = id - col * K;
    float v;
    if constexpr (NCAT) {
        v = (col < 64) ? W1[(size_t)k * 64 + col] : W2[(size_t)k * 64 + (col - 64)];
    } else {
        v = (k < KA) ? W1[(size_t)k * 128 + col] : W2[(size_t)(k - KA) * 128 + col];
    }
    int chunk = k >> 5, kk = k & 31;
    int kg4 = kk >> 3, j = kk & 7;
    int ct = col >> 4, lr = col & 15;
    size_t dst = ((size_t)(chunk * 8 + ct) * 64 + kg4 * 16 + lr) * 8 + j;
    hi[dst] = bf16_rne(v);
}

// ---------------- MFMA GEMM, K-SPLIT across waves ----------------
// C = (Ah+Al)@Wh (A fp32-effective via hi/lo split; W bf16).
// Block: 256 thr = 4 waves over 32 rows: waves {0,1} = K-half 0 (rows 0-15 /
// 16-31), waves {2,3} = K-half 1. Each wave runs NCH/2 chunks (half the
// serial chain of R16); grid 1563 -> 24.4 waves/CU offered (2x R16 TLP).
// Half-1 partials deposited in LDS [32][130] (2-way banks), one barrier,
// half-0 adds + epilogue. Single W buffer, A prefetched 1 chunk ahead.
// MFMA layouts (m89): A[j]=A[lr][kg4*8+j], B[j]=B[kg4*8+j][lr], D[j]=C[kg4*4+j][lr].
// BFOUT: 1 = also write bf16 copy (stride 128); 2 = bf16 copy cols 0..63.

template <int K, int KA, int NCAT, int RELU, int BFOUT>
__launch_bounds__(256, 5)
__global__ void k_mgemm(const float* __restrict__ inA, const float* __restrict__ inB,
                        const ushort* __restrict__ Whi,
                        const float* __restrict__ bias, float* __restrict__ out,
                        ushort* __restrict__ bfout) {
    constexpr int KB = K - KA;
    constexpr int NCH = K / 32;
    constexpr int NCHH = NCH / 2;   // chunks per K-half (2 or 4)
    __shared__ float sC[32][130];

    int tid = threadIdx.x;
    int wave = tid >> 6, lane = tid & 63;
    int lr  = lane & 15;
    int kg4 = lane >> 4;
    int half = wave >> 1;           // K-half
    int wq   = wave & 1;            // row-group
    int rbase = blockIdx.x * 32 + wq * 16;
    int row = min(rbase + lr, NN - 1);
    int rloc = wq * 16 + kg4 * 4;   // LDS row base for this lane's outputs

    f32x4 acc[8];
    #pragma unroll
    for (int ct = 0; ct < 8; ct++) acc[ct] = (f32x4){0.f, 0.f, 0.f, 0.f};

    const ushort* baseH = Whi + (size_t)lane * 8;

    auto loadA = [&](int chunk, float4& v0, float4& v1) {
        int kg2 = chunk * 32 + kg4 * 8;
        if constexpr (NCAT) {
            v0 = *(const float4*)&inA[(size_t)row * K + kg2];
            v1 = *(const float4*)&inA[(size_t)row * K + kg2 + 4];
        } else {
            if (kg2 < KA) v0 = *(const float4*)&inA[(size_t)row * KA + kg2];
            else          v0 = *(const float4*)&inB[(size_t)row * KB + (kg2 - KA)];
            if (kg2 + 4 < KA) v1 = *(const float4*)&inA[(size_t)row * KA + kg2 + 4];
            else              v1 = *(const float4*)&inB[(size_t)row * KB + (kg2 + 4 - KA)];
        }
    };

    int c0 = half * NCHH;
    float4 aC0, aC1, aN0, aN1;
    loadA(c0, aC0, aC1);

    #pragma unroll
    for (int cc = 0; cc < NCHH; cc++) {
        int c = c0 + cc;
        if (cc + 1 < NCHH) loadA(c + 1, aN0, aN1);  // prefetch next A
        bf16x8 ah, al;
        {
            float av[8] = {aC0.x, aC0.y, aC0.z, aC0.w, aC1.x, aC1.y, aC1.z, aC1.w};
            #pragma unroll
            for (int j = 0; j < 8; j++) {
                ushort h = bf16_rne(av[j]);
                ushort l = bf16_rne(av[j] - bf16_to_f(h));
                ah[j] = (short)h;
                al[j] = (short)l;
            }
        }
        const ushort* ph = baseH + (size_t)c * 4096;
        #pragma unroll
        for (int ct = 0; ct < 8; ct++) {
            bf16x8 wh = *(const bf16x8*)(ph + ct * 512);
            acc[ct] = __builtin_amdgcn_mfma_f32_16x16x32_bf16(ah, wh, acc[ct], 0, 0, 0);
            acc[ct] = __builtin_amdgcn_mfma_f32_16x16x32_bf16(al, wh, acc[ct], 0, 0, 0);
        }
        aC0 = aN0; aC1 = aN1;
    }

    // K-half 1 deposits partials; K-half 0 combines + epilogue
    if (half == 1) {
        #pragma unroll
        for (int ct = 0; ct < 8; ct++)
            #pragma unroll
            for (int j = 0; j < 4; j++)
                sC[rloc + j][ct * 16 + lr] = acc[ct][j];
    }
    __syncthreads();
    if (half == 1) return;

    float bc[8];
    #pragma unroll
    for (int ct = 0; ct < 8; ct++) {
        int c = ct * 16 + lr;
        if constexpr (NCAT) bc[ct] = (c < 64) ? 0.f : bias[c - 64];
        else bc[ct] = bias[c];
    }
    #pragma unroll
    for (int j = 0; j < 4; j++) {
        int n = rbase + kg4 * 4 + j;
        if (n < NN) {
            float* orow = &out[(size_t)n * 128 + lr];
            #pragma unroll
            for (int ct = 0; ct < 8; ct++) {
                float v = acc[ct][j] + sC[rloc + j][ct * 16 + lr] + bc[ct];
                if (RELU) v = fmaxf(v, 0.f);
                orow[ct * 16] = v;
                if constexpr (BFOUT == 1) bfout[(size_t)n * 128 + ct * 16 + lr] = bf16_rne(v);
                if constexpr (BFOUT == 2) { if (ct < 4) bfout[(size_t)n * 64 + ct * 16 + lr] = bf16_rne(v); }
            }
        }
    }
}

// ---------------- decode ----------------

__global__ void k_decode(const int* __restrict__ eli, const float* __restrict__ z,
                         float* __restrict__ out) {
    int w = blockIdx.x * 4 + (threadIdx.x >> 6);
    int lane = threadIdx.x & 63;
    int sub = lane >> 4, li = lane & 15;
    int e0 = w * 8 + sub;
    int e1 = e0 + 4;
    float s0 = 0.f, s1 = 0.f;
    if (e0 < NL) {
        int a = eli[e0], b = eli[NL + e0];
        float4 va = *(const float4*)&z[(size_t)a * 64 + li * 4];
        float4 vb = *(const float4*)&z[(size_t)b * 64 + li * 4];
        s0 = va.x * vb.x + va.y * vb.y + va.z * vb.z + va.w * vb.w;
    }
    if (e1 < NL) {
        int a = eli[e1], b = eli[NL + e1];
        float4 va = *(const float4*)&z[(size_t)a * 64 + li * 4];
        float4 vb = *(const float4*)&z[(size_t)b * 64 + li * 4];
        s1 = va.x * vb.x + va.y * vb.y + va.z * vb.z + va.w * vb.w;
    }
    #pragma unroll
    for (int off = 1; off < 16; off <<= 1) {
        s0 += __shfl_xor(s0, off, 64);
        s1 += __shfl_xor(s1, off, 64);
    }
    if (li == 0) {
        if (e0 < NL) out[e0] = s0;
        if (e1 < NL) out[e1] = s1;
    }
}

// ---------------- launch ----------------

extern "C" void kernel_launch(void* const* d_in, const int* in_sizes, int n_in,
                              void* d_out, int out_size, void* d_ws, size_t ws_size,
                              hipStream_t stream) {
    const float* x   = (const float*)d_in[0];
    const int*   edge = (const int*)d_in[1];   // [2, NE]
    const int*   eli  = (const int*)d_in[2];   // [2, NL]
    const float* Wl1 = (const float*)d_in[3];
    const float* Wr1 = (const float*)d_in[4];
    const float* b1  = (const float*)d_in[5];
    const float* Wl2 = (const float*)d_in[6];
    const float* Wr2 = (const float*)d_in[7];
    const float* b2  = (const float*)d_in[8];
    const float* Wl3 = (const float*)d_in[9];
    const float* Wr3 = (const float*)d_in[10];
    const float* b3  = (const float*)d_in[11];
    float* out = (float*)d_out;

    char* w = (char*)d_ws;
    auto carve = [&](size_t bytes) {
        char* p = w;
        w += (bytes + 255) & ~(size_t)255;
        return p;
    };
    int*    rowptr = (int*)carve((NN + 1) * sizeof(int));
    int*    counts = (int*)carve(NN * sizeof(int));
    int*    rank   = (int*)carve(NE * sizeof(int));
    int*    csr    = (int*)carve(NE * sizeof(int));
    int*    bsum   = (int*)carve(256 * sizeof(int));
    float*  M      = (float*)carve((size_t)NN * 64 * sizeof(float));   // mean1, later z
    float*  A      = (float*)carve((size_t)NN * 128 * sizeof(float));  // h1
    float*  B      = (float*)carve((size_t)NN * 128 * sizeof(float));  // mean2, later pq
    float*  C      = (float*)carve((size_t)NN * 128 * sizeof(float));  // h2
    ushort* xb     = (ushort*)carve((size_t)NN * 64 * sizeof(ushort));  // bf16 x
    ushort* h1b    = (ushort*)carve((size_t)NN * 128 * sizeof(ushort)); // bf16 h1
    ushort* pb     = (ushort*)carve((size_t)NN * 64 * sizeof(ushort));  // bf16 p
    ushort* W1h    = (ushort*)carve(128 * 128 * sizeof(ushort));
    ushort* W2h    = (ushort*)carve(128 * 256 * sizeof(ushort));
    ushort* W3h    = (ushort*)carve(128 * 128 * sizeof(ushort));

    const int* src = edge;
    const int* tgt = edge + NE;

    // prep: weight bf16 fragment layout + x bf16 cast
    k_wsplit<128, 64, 0><<<64, 256, 0, stream>>>(Wl1, Wr1, W1h);
    k_wsplit<256, 128, 0><<<128, 256, 0, stream>>>(Wl2, Wr2, W2h);
    k_wsplit<128, 128, 1><<<64, 256, 0, stream>>>(Wl3, Wr3, W3h);
    k_xcast<<<(NN * 8 + 255) / 256, 256, 0, stream>>>(x, xb, NN * 8);

    // CSR build
    hipMemsetAsync(counts, 0, NN * sizeof(int), stream);
    k_count<<<(NE + 255) / 256, 256, 0, stream>>>(tgt, counts, rank);
    k_scan1<<<NB_SCAN, 256, 0, stream>>>(counts, bsum);
    k_scan2<<<1, 256, 0, stream>>>(bsum, NB_SCAN);
    k_scan3<<<NB_SCAN, 256, 0, stream>>>(counts, bsum, rowptr);
    k_fill<<<(NE + 255) / 256, 256, 0, stream>>>(src, tgt, rowptr, rank, csr);

    const int MG = (NN + 31) / 32;  // 1563 blocks (K-split tiling)

    // layer 1: mean1 = mean(x); h1 = relu([mean1|x]@[Wl1;Wr1]+b1)  (+h1 bf16 copy)
    k_aggb<64><<<(NN + 3) / 4, 256, 0, stream>>>(xb, nullptr, 0, M, 64, rowptr, csr);
    k_mgemm<128, 64, 0, 1, 1><<<MG, 256, 0, stream>>>(M, x, W1h, b1, A, h1b);

    // layer 2: mean2 = mean(h1); h2 = relu([mean2|h1]@[Wl2;Wr2]+b2)
    k_aggb<128><<<(NN + 3) / 4, 256, 0, stream>>>(h1b, nullptr, 0, B, 128, rowptr, csr);
    k_mgemm<256, 128, 0, 1, 0><<<MG, 256, 0, stream>>>(B, A, W2h, b2, C, nullptr);

    // layer 3: pq = h2 @ [Wl3 | Wr3] (+p bf16 copy); z = mean(p) + q
    k_mgemm<128, 128, 1, 0, 2><<<MG, 256, 0, stream>>>(C, nullptr, W3h, b3, B, pb);
    k_aggb<64><<<(NN + 3) / 4, 256, 0, stream>>>(pb, B + 64, 128, M, 64, rowptr, csr);

    // decode: out[l] = dot(z[a], z[b])
    k_decode<<<(NL + 31) / 32, 256, 0, stream>>>(eli, M, out);
}

// Round 18
// 205.733 us; speedup vs baseline: 1.1440x; 1.0157x over previous
//
#include <hip/hip_runtime.h>

#define NN 50000
#define NE 800000
#define NL 200000
#define NB_SCAN 196  // ceil(50000/256)

typedef __attribute__((ext_vector_type(8))) short bf16x8;
typedef __attribute__((ext_vector_type(4))) float f32x4;

__device__ __forceinline__ ushort bf16_rne(float f) {
    union { float f; unsigned u; } v; v.f = f;
    unsigned r = v.u + 0x7FFF + ((v.u >> 16) & 1);
    return (ushort)(r >> 16);
}
__device__ __forceinline__ float bf16_to_f(ushort h) {
    union { unsigned u; float f; } v; v.u = ((unsigned)h) << 16;
    return v.f;
}
__device__ __forceinline__ float lo_f(unsigned u) {
    union { unsigned u; float f; } v; v.u = u << 16;
    return v.f;
}
__device__ __forceinline__ float hi_f(unsigned u) {
    union { unsigned u; float f; } v; v.u = u & 0xffff0000u;
    return v.f;
}

// ---------------- CSR build ----------------

__global__ void k_count(const int* __restrict__ tgt, int* __restrict__ counts,
                        int* __restrict__ rank) {
    int e = blockIdx.x * blockDim.x + threadIdx.x;
    if (e < NE) rank[e] = atomicAdd(&counts[tgt[e]], 1);
}

__global__ void k_scan1(const int* __restrict__ counts, int* __restrict__ bsum) {
    int i = blockIdx.x * 256 + threadIdx.x;
    int v = (i < NN) ? counts[i] : 0;
    #pragma unroll
    for (int off = 32; off; off >>= 1) v += __shfl_down(v, off, 64);
    __shared__ int ws4[4];
    int wave = threadIdx.x >> 6, lane = threadIdx.x & 63;
    if (lane == 0) ws4[wave] = v;
    __syncthreads();
    if (threadIdx.x == 0) bsum[blockIdx.x] = ws4[0] + ws4[1] + ws4[2] + ws4[3];
}

__global__ void k_scan2(int* __restrict__ bsum, int nb) {
    __shared__ int s[256];
    int t = threadIdx.x;
    int v = (t < nb) ? bsum[t] : 0;
    s[t] = v;
    __syncthreads();
    for (int off = 1; off < 256; off <<= 1) {
        int a = (t >= off) ? s[t - off] : 0;
        __syncthreads();
        s[t] += a;
        __syncthreads();
    }
    if (t < nb) bsum[t] = s[t] - v;  // exclusive
}

__global__ void k_scan3(const int* __restrict__ counts, const int* __restrict__ boff,
                        int* __restrict__ rowptr) {
    __shared__ int s[256];
    int t = threadIdx.x;
    int i = blockIdx.x * 256 + t;
    int v = (i < NN) ? counts[i] : 0;
    s[t] = v;
    __syncthreads();
    for (int off = 1; off < 256; off <<= 1) {
        int a = (t >= off) ? s[t - off] : 0;
        __syncthreads();
        s[t] += a;
        __syncthreads();
    }
    int excl = s[t] - v + boff[blockIdx.x];
    if (i < NN) rowptr[i] = excl;
    if (i == NN - 1) rowptr[NN] = excl + v;  // == NE
}

__global__ void k_fill(const int* __restrict__ src, const int* __restrict__ tgt,
                       const int* __restrict__ rowptr, const int* __restrict__ rank,
                       int* __restrict__ csr) {
    int e = blockIdx.x * blockDim.x + threadIdx.x;
    if (e < NE) csr[rowptr[tgt[e]] + rank[e]] = src[e];
}

// ---------------- x -> bf16 cast ----------------

__global__ void k_xcast(const float* __restrict__ x, ushort* __restrict__ xb, int n8) {
    int i = blockIdx.x * 256 + threadIdx.x;
    if (i >= n8) return;
    float4 v0 = *(const float4*)&x[i * 8];
    float4 v1 = *(const float4*)&x[i * 8 + 4];
    ushort h[8] = {bf16_rne(v0.x), bf16_rne(v0.y), bf16_rne(v0.z), bf16_rne(v0.w),
                   bf16_rne(v1.x), bf16_rne(v1.y), bf16_rne(v1.z), bf16_rne(v1.w)};
    *(bf16x8*)&xb[i * 8] = *(bf16x8*)h;
}

// ---------------- CSR gather-mean aggregation, D=64, 2-stream ----------------
// OBF=0: fp32 out. OBF=1: bf16 out (+fp32 addp first).

template <int OBF>
__global__ void k_aggb64(const ushort* __restrict__ in,
                         const float* __restrict__ addp, int addStride,
                         float* __restrict__ outF, ushort* __restrict__ outB,
                         const int* __restrict__ rowptr, const int* __restrict__ csr) {
    constexpr int D = 64, LPR = 8, EPW = 8;
    int node = blockIdx.x * 4 + (threadIdx.x >> 6);
    int lane = threadIdx.x & 63;
    if (node >= NN) return;
    int sub = lane / LPR;
    int li  = lane % LPR;
    int r0 = rowptr[node], r1 = rowptr[node + 1];

    float a[8] = {0.f, 0.f, 0.f, 0.f, 0.f, 0.f, 0.f, 0.f};
    float b[8] = {0.f, 0.f, 0.f, 0.f, 0.f, 0.f, 0.f, 0.f};
    int e0 = r0 + sub;
    int e1 = e0 + EPW;
    int i0 = (e0 < r1) ? csr[e0] : 0;
    int i1 = (e1 < r1) ? csr[e1] : 0;
    while (e1 < r1) {
        int e0n = e0 + 2 * EPW, e1n = e1 + 2 * EPW;
        int i0n = (e0n < r1) ? csr[e0n] : 0;
        int i1n = (e1n < r1) ? csr[e1n] : 0;
        uint4 v0 = *(const uint4*)(in + (size_t)i0 * D + li * 8);
        uint4 v1 = *(const uint4*)(in + (size_t)i1 * D + li * 8);
        a[0] += lo_f(v0.x); a[1] += hi_f(v0.x); a[2] += lo_f(v0.y); a[3] += hi_f(v0.y);
        a[4] += lo_f(v0.z); a[5] += hi_f(v0.z); a[6] += lo_f(v0.w); a[7] += hi_f(v0.w);
        b[0] += lo_f(v1.x); b[1] += hi_f(v1.x); b[2] += lo_f(v1.y); b[3] += hi_f(v1.y);
        b[4] += lo_f(v1.z); b[5] += hi_f(v1.z); b[6] += lo_f(v1.w); b[7] += hi_f(v1.w);
        e0 = e0n; e1 = e1n; i0 = i0n; i1 = i1n;
    }
    if (e0 < r1) {
        uint4 v0 = *(const uint4*)(in + (size_t)i0 * D + li * 8);
        a[0] += lo_f(v0.x); a[1] += hi_f(v0.x); a[2] += lo_f(v0.y); a[3] += hi_f(v0.y);
        a[4] += lo_f(v0.z); a[5] += hi_f(v0.z); a[6] += lo_f(v0.w); a[7] += hi_f(v0.w);
    }
    #pragma unroll
    for (int j = 0; j < 8; j++) a[j] += b[j];
    #pragma unroll
    for (int off = LPR; off < 64; off <<= 1)
        #pragma unroll
        for (int j = 0; j < 8; j++) a[j] += __shfl_xor(a[j], off, 64);
    if (sub == 0) {
        float inv = 1.0f / fmaxf((float)(r1 - r0), 1.0f);
        #pragma unroll
        for (int j = 0; j < 8; j++) a[j] *= inv;
        if (addp) {
            float4 p0 = *(const float4*)&addp[(size_t)node * addStride + li * 8];
            float4 p1 = *(const float4*)&addp[(size_t)node * addStride + li * 8 + 4];
            a[0] += p0.x; a[1] += p0.y; a[2] += p0.z; a[3] += p0.w;
            a[4] += p1.x; a[5] += p1.y; a[6] += p1.z; a[7] += p1.w;
        }
        if constexpr (OBF) {
            ushort h[8];
            #pragma unroll
            for (int j = 0; j < 8; j++) h[j] = bf16_rne(a[j]);
            *(bf16x8*)&outB[(size_t)node * D + li * 8] = *(bf16x8*)h;
        } else {
            *(float4*)&outF[(size_t)node * D + li * 8]     = make_float4(a[0], a[1], a[2], a[3]);
            *(float4*)&outF[(size_t)node * D + li * 8 + 4] = make_float4(a[4], a[5], a[6], a[7]);
        }
    }
}

// ---------------- CSR gather-mean aggregation, D=128, 4-stream ----------------
// 4 edge slots x 4 streams = 16 rows in flight (covers deg~16 in one pass).

__global__ void k_aggb128(const ushort* __restrict__ in, float* __restrict__ out,
                          const int* __restrict__ rowptr, const int* __restrict__ csr) {
    constexpr int D = 128, LPR = 16, EPW = 4;
    int node = blockIdx.x * 4 + (threadIdx.x >> 6);
    int lane = threadIdx.x & 63;
    if (node >= NN) return;
    int sub = lane / LPR;
    int li  = lane % LPR;
    int r0 = rowptr[node], r1 = rowptr[node + 1];

    float a[8] = {0.f, 0.f, 0.f, 0.f, 0.f, 0.f, 0.f, 0.f};
    float b[8] = {0.f, 0.f, 0.f, 0.f, 0.f, 0.f, 0.f, 0.f};
    int e0 = r0 + sub, e1 = e0 + EPW, e2 = e0 + 2 * EPW, e3 = e0 + 3 * EPW;
    int i0 = (e0 < r1) ? csr[e0] : 0;
    int i1 = (e1 < r1) ? csr[e1] : 0;
    int i2 = (e2 < r1) ? csr[e2] : 0;
    int i3 = (e3 < r1) ? csr[e3] : 0;

#define ACC(A, V)                                                      \
    A[0] += lo_f(V.x); A[1] += hi_f(V.x); A[2] += lo_f(V.y); A[3] += hi_f(V.y); \
    A[4] += lo_f(V.z); A[5] += hi_f(V.z); A[6] += lo_f(V.w); A[7] += hi_f(V.w);

    while (e3 < r1) {
        int e0n = e0 + 16, e1n = e1 + 16, e2n = e2 + 16, e3n = e3 + 16;
        int i0n = (e0n < r1) ? csr[e0n] : 0;
        int i1n = (e1n < r1) ? csr[e1n] : 0;
        int i2n = (e2n < r1) ? csr[e2n] : 0;
        int i3n = (e3n < r1) ? csr[e3n] : 0;
        uint4 v0 = *(const uint4*)(in + (size_t)i0 * D + li * 8);
        uint4 v1 = *(const uint4*)(in + (size_t)i1 * D + li * 8);
        uint4 v2 = *(const uint4*)(in + (size_t)i2 * D + li * 8);
        uint4 v3 = *(const uint4*)(in + (size_t)i3 * D + li * 8);
        ACC(a, v0) ACC(b, v1) ACC(a, v2) ACC(b, v3)
        e0 = e0n; e1 = e1n; e2 = e2n; e3 = e3n;
        i0 = i0n; i1 = i1n; i2 = i2n; i3 = i3n;
    }
    // tail: at most one gather per remaining stream
    if (e0 < r1) { uint4 v = *(const uint4*)(in + (size_t)i0 * D + li * 8); ACC(a, v) }
    if (e1 < r1) { uint4 v = *(const uint4*)(in + (size_t)i1 * D + li * 8); ACC(b, v) }
    if (e2 < r1) { uint4 v = *(const uint4*)(in + (size_t)i2 * D + li * 8); ACC(a, v) }
#undef ACC
    #pragma unroll
    for (int j = 0; j < 8; j++) a[j] += b[j];
    #pragma unroll
    for (int off = LPR; off < 64; off <<= 1)
        #pragma unroll
        for (int j = 0; j < 8; j++) a[j] += __shfl_xor(a[j], off, 64);
    if (sub == 0) {
        float inv = 1.0f / fmaxf((float)(r1 - r0), 1.0f);
        #pragma unroll
        for (int j = 0; j < 8; j++) a[j] *= inv;
        *(float4*)&out[(size_t)node * D + li * 8]     = make_float4(a[0], a[1], a[2], a[3]);
        *(float4*)&out[(size_t)node * D + li * 8 + 4] = make_float4(a[4], a[5], a[6], a[7]);
    }
}

// ---------------- weight fragment layout (bf16, hi only) ----------------
// frag[chunk][ct][lane][j] -> W[chunk*32 + (lane>>4)*8 + j][ct*16 + (lane&15)].

template <int K, int KA, int NCAT>
__global__ void k_wsplit(const float* __restrict__ W1, const float* __restrict__ W2,
                         ushort* __restrict__ hi) {
    int id = blockIdx.x * 256 + threadIdx.x;
    if (id >= 128 * K) return;
    int col = id / K, k = id - col * K;
    float v;
    if constexpr (NCAT) {
        v = (col < 64) ? W1[(size_t)k * 64 + col] : W2[(size_t)k * 64 + (col - 64)];
    } else {
        v = (k < KA) ? W1[(size_t)k * 128 + col] : W2[(size_t)(k - KA) * 128 + col];
    }
    int chunk = k >> 5, kk = k & 31;
    int kg4 = kk >> 3, j = kk & 7;
    int ct = col >> 4, lr = col & 15;
    size_t dst = ((size_t)(chunk * 8 + ct) * 64 + kg4 * 16 + lr) * 8 + j;
    hi[dst] = bf16_rne(v);
}

// ---------------- MFMA GEMM, K-SPLIT across waves (R17 structure, frozen) ----------------
// C = (Ah+Al)@Wh (A fp32-effective via hi/lo split; W bf16).

template <int K, int KA, int NCAT, int RELU, int BFOUT>
__launch_bounds__(256, 5)
__global__ void k_mgemm(const float* __restrict__ inA, const float* __restrict__ inB,
                        const ushort* __restrict__ Whi,
                        const float* __restrict__ bias, float* __restrict__ out,
                        ushort* __restrict__ bfout) {
    constexpr int KB = K - KA;
    constexpr int NCH = K / 32;
    constexpr int NCHH = NCH / 2;
    __shared__ float sC[32][130];

    int tid = threadIdx.x;
    int wave = tid >> 6, lane = tid & 63;
    int lr  = lane & 15;
    int kg4 = lane >> 4;
    int half = wave >> 1;
    int wq   = wave & 1;
    int rbase = blockIdx.x * 32 + wq * 16;
    int row = min(rbase + lr, NN - 1);
    int rloc = wq * 16 + kg4 * 4;

    f32x4 acc[8];
    #pragma unroll
    for (int ct = 0; ct < 8; ct++) acc[ct] = (f32x4){0.f, 0.f, 0.f, 0.f};

    const ushort* baseH = Whi + (size_t)lane * 8;

    auto loadA = [&](int chunk, float4& v0, float4& v1) {
        int kg2 = chunk * 32 + kg4 * 8;
        if constexpr (NCAT) {
            v0 = *(const float4*)&inA[(size_t)row * K + kg2];
            v1 = *(const float4*)&inA[(size_t)row * K + kg2 + 4];
        } else {
            if (kg2 < KA) v0 = *(const float4*)&inA[(size_t)row * KA + kg2];
            else          v0 = *(const float4*)&inB[(size_t)row * KB + (kg2 - KA)];
            if (kg2 + 4 < KA) v1 = *(const float4*)&inA[(size_t)row * KA + kg2 + 4];
            else              v1 = *(const float4*)&inB[(size_t)row * KB + (kg2 + 4 - KA)];
        }
    };

    int c0 = half * NCHH;
    float4 aC0, aC1, aN0, aN1;
    loadA(c0, aC0, aC1);

    #pragma unroll
    for (int cc = 0; cc < NCHH; cc++) {
        int c = c0 + cc;
        if (cc + 1 < NCHH) loadA(c + 1, aN0, aN1);
        bf16x8 ah, al;
        {
            float av[8] = {aC0.x, aC0.y, aC0.z, aC0.w, aC1.x, aC1.y, aC1.z, aC1.w};
            #pragma unroll
            for (int j = 0; j < 8; j++) {
                ushort h = bf16_rne(av[j]);
                ushort l = bf16_rne(av[j] - bf16_to_f(h));
                ah[j] = (short)h;
                al[j] = (short)l;
            }
        }
        const ushort* ph = baseH + (size_t)c * 4096;
        #pragma unroll
        for (int ct = 0; ct < 8; ct++) {
            bf16x8 wh = *(const bf16x8*)(ph + ct * 512);
            acc[ct] = __builtin_amdgcn_mfma_f32_16x16x32_bf16(ah, wh, acc[ct], 0, 0, 0);
            acc[ct] = __builtin_amdgcn_mfma_f32_16x16x32_bf16(al, wh, acc[ct], 0, 0, 0);
        }
        aC0 = aN0; aC1 = aN1;
    }

    if (half == 1) {
        #pragma unroll
        for (int ct = 0; ct < 8; ct++)
            #pragma unroll
            for (int j = 0; j < 4; j++)
                sC[rloc + j][ct * 16 + lr] = acc[ct][j];
    }
    __syncthreads();
    if (half == 1) return;

    float bc[8];
    #pragma unroll
    for (int ct = 0; ct < 8; ct++) {
        int c = ct * 16 + lr;
        if constexpr (NCAT) bc[ct] = (c < 64) ? 0.f : bias[c - 64];
        else bc[ct] = bias[c];
    }
    #pragma unroll
    for (int j = 0; j < 4; j++) {
        int n = rbase + kg4 * 4 + j;
        if (n < NN) {
            float* orow = &out[(size_t)n * 128 + lr];
            #pragma unroll
            for (int ct = 0; ct < 8; ct++) {
                float v = acc[ct][j] + sC[rloc + j][ct * 16 + lr] + bc[ct];
                if (RELU) v = fmaxf(v, 0.f);
                orow[ct * 16] = v;
                if constexpr (BFOUT == 1) bfout[(size_t)n * 128 + ct * 16 + lr] = bf16_rne(v);
                if constexpr (BFOUT == 2) { if (ct < 4) bfout[(size_t)n * 64 + ct * 16 + lr] = bf16_rne(v); }
            }
        }
    }
}

// ---------------- decode (bf16 z, 8 edges/wave) ----------------
// Slot = 8 lanes x uint4 (one 128B z-row); slot pairs (a,b) exchange via
// shfl_xor(8); two streams (e0, e0+4) -> 16 row-gathers in flight per wave.

__global__ void k_decode(const int* __restrict__ eli, const ushort* __restrict__ zb,
                         float* __restrict__ out) {
    int w = blockIdx.x * 4 + (threadIdx.x >> 6);
    int lane = threadIdx.x & 63;
    int slot = lane >> 3;       // 0..7
    int li   = lane & 7;
    int ep   = slot & 1;        // endpoint 0=a, 1=b
    int e0 = w * 8 + (slot >> 1);
    int e1 = e0 + 4;
    int idx0 = (e0 < NL) ? eli[ep * NL + e0] : 0;
    int idx1 = (e1 < NL) ? eli[ep * NL + e1] : 0;
    uint4 v0 = *(const uint4*)(zb + (size_t)idx0 * 64 + li * 8);
    uint4 v1 = *(const uint4*)(zb + (size_t)idx1 * 64 + li * 8);
    uint4 p0, p1;
    p0.x = __shfl_xor((int)v0.x, 8, 64); p0.y = __shfl_xor((int)v0.y, 8, 64);
    p0.z = __shfl_xor((int)v0.z, 8, 64); p0.w = __shfl_xor((int)v0.w, 8, 64);
    p1.x = __shfl_xor((int)v1.x, 8, 64); p1.y = __shfl_xor((int)v1.y, 8, 64);
    p1.z = __shfl_xor((int)v1.z, 8, 64); p1.w = __shfl_xor((int)v1.w, 8, 64);
    float s0 = lo_f(v0.x) * lo_f(p0.x) + hi_f(v0.x) * hi_f(p0.x)
             + lo_f(v0.y) * lo_f(p0.y) + hi_f(v0.y) * hi_f(p0.y)
             + lo_f(v0.z) * lo_f(p0.z) + hi_f(v0.z) * hi_f(p0.z)
             + lo_f(v0.w) * lo_f(p0.w) + hi_f(v0.w) * hi_f(p0.w);
    float s1 = lo_f(v1.x) * lo_f(p1.x) + hi_f(v1.x) * hi_f(p1.x)
             + lo_f(v1.y) * lo_f(p1.y) + hi_f(v1.y) * hi_f(p1.y)
             + lo_f(v1.z) * lo_f(p1.z) + hi_f(v1.z) * hi_f(p1.z)
             + lo_f(v1.w) * lo_f(p1.w) + hi_f(v1.w) * hi_f(p1.w);
    #pragma unroll
    for (int off = 1; off < 8; off <<= 1) {
        s0 += __shfl_xor(s0, off, 64);
        s1 += __shfl_xor(s1, off, 64);
    }
    if (li == 0 && ep == 0) {
        if (e0 < NL) out[e0] = s0;
        if (e1 < NL) out[e1] = s1;
    }
}

// ---------------- launch ----------------

extern "C" void kernel_launch(void* const* d_in, const int* in_sizes, int n_in,
                              void* d_out, int out_size, void* d_ws, size_t ws_size,
                              hipStream_t stream) {
    const float* x   = (const float*)d_in[0];
    const int*   edge = (const int*)d_in[1];   // [2, NE]
    const int*   eli  = (const int*)d_in[2];   // [2, NL]
    const float* Wl1 = (const float*)d_in[3];
    const float* Wr1 = (const float*)d_in[4];
    const float* b1  = (const float*)d_in[5];
    const float* Wl2 = (const float*)d_in[6];
    const float* Wr2 = (const float*)d_in[7];
    const float* b2  = (const float*)d_in[8];
    const float* Wl3 = (const float*)d_in[9];
    const float* Wr3 = (const float*)d_in[10];
    const float* b3  = (const float*)d_in[11];
    float* out = (float*)d_out;

    char* w = (char*)d_ws;
    auto carve = [&](size_t bytes) {
        char* p = w;
        w += (bytes + 255) & ~(size_t)255;
        return p;
    };
    int*    rowptr = (int*)carve((NN + 1) * sizeof(int));
    int*    counts = (int*)carve(NN * sizeof(int));
    int*    rank   = (int*)carve(NE * sizeof(int));
    int*    csr    = (int*)carve(NE * sizeof(int));
    int*    bsum   = (int*)carve(256 * sizeof(int));
    float*  M      = (float*)carve((size_t)NN * 64 * sizeof(float));   // mean1
    float*  A      = (float*)carve((size_t)NN * 128 * sizeof(float));  // h1
    float*  B      = (float*)carve((size_t)NN * 128 * sizeof(float));  // mean2, later pq
    float*  C      = (float*)carve((size_t)NN * 128 * sizeof(float));  // h2
    ushort* xb     = (ushort*)carve((size_t)NN * 64 * sizeof(ushort));  // bf16 x
    ushort* h1b    = (ushort*)carve((size_t)NN * 128 * sizeof(ushort)); // bf16 h1
    ushort* pb     = (ushort*)carve((size_t)NN * 64 * sizeof(ushort));  // bf16 p
    ushort* zb     = (ushort*)carve((size_t)NN * 64 * sizeof(ushort));  // bf16 z
    ushort* W1h    = (ushort*)carve(128 * 128 * sizeof(ushort));
    ushort* W2h    = (ushort*)carve(128 * 256 * sizeof(ushort));
    ushort* W3h    = (ushort*)carve(128 * 128 * sizeof(ushort));

    const int* src = edge;
    const int* tgt = edge + NE;

    // prep: weight bf16 fragment layout + x bf16 cast
    k_wsplit<128, 64, 0><<<64, 256, 0, stream>>>(Wl1, Wr1, W1h);
    k_wsplit<256, 128, 0><<<128, 256, 0, stream>>>(Wl2, Wr2, W2h);
    k_wsplit<128, 128, 1><<<64, 256, 0, stream>>>(Wl3, Wr3, W3h);
    k_xcast<<<(NN * 8 + 255) / 256, 256, 0, stream>>>(x, xb, NN * 8);

    // CSR build
    hipMemsetAsync(counts, 0, NN * sizeof(int), stream);
    k_count<<<(NE + 255) / 256, 256, 0, stream>>>(tgt, counts, rank);
    k_scan1<<<NB_SCAN, 256, 0, stream>>>(counts, bsum);
    k_scan2<<<1, 256, 0, stream>>>(bsum, NB_SCAN);
    k_scan3<<<NB_SCAN, 256, 0, stream>>>(counts, bsum, rowptr);
    k_fill<<<(NE + 255) / 256, 256, 0, stream>>>(src, tgt, rowptr, rank, csr);

    const int MG = (NN + 31) / 32;  // 1563 blocks

    // layer 1: mean1 = mean(x); h1 = relu([mean1|x]@[Wl1;Wr1]+b1)  (+h1 bf16 copy)
    k_aggb64<0><<<(NN + 3) / 4, 256, 0, stream>>>(xb, nullptr, 0, M, nullptr, rowptr, csr);
    k_mgemm<128, 64, 0, 1, 1><<<MG, 256, 0, stream>>>(M, x, W1h, b1, A, h1b);

    // layer 2: mean2 = mean(h1) [4-stream]; h2 = relu([mean2|h1]@[Wl2;Wr2]+b2)
    k_aggb128<<<(NN + 3) / 4, 256, 0, stream>>>(h1b, B, rowptr, csr);
    k_mgemm<256, 128, 0, 1, 0><<<MG, 256, 0, stream>>>(B, A, W2h, b2, C, nullptr);

    // layer 3: pq = h2 @ [Wl3 | Wr3] (+p bf16 copy); z = mean(p) + q  -> bf16 zb
    k_mgemm<128, 128, 1, 0, 2><<<MG, 256, 0, stream>>>(C, nullptr, W3h, b3, B, pb);
    k_aggb64<1><<<(NN + 3) / 4, 256, 0, stream>>>(pb, B + 64, 128, nullptr, zb, rowptr, csr);

    // decode: out[l] = dot(z[a], z[b])  (bf16 z, half gather volume)
    k_decode<<<(NL + 31) / 32, 256, 0, stream>>>(eli, zb, out);
}